// Round 1
// baseline (1059.859 us; speedup 1.0000x reference)
//
#include <hip/hip_runtime.h>

typedef __attribute__((ext_vector_type(8))) short short8;
typedef __attribute__((ext_vector_type(4))) float f32x4;

__device__ __forceinline__ unsigned short f2bf(float f) {
  unsigned int u = __float_as_uint(f);
  u = u + 0x7FFFu + ((u >> 16) & 1u);
  return (unsigned short)(u >> 16);
}
__device__ __forceinline__ float bf2f(unsigned short b) {
  return __uint_as_float(((unsigned int)b) << 16);
}
__device__ __forceinline__ f32x4 mfma16(short8 a, short8 b, f32x4 c) {
  return __builtin_amdgcn_mfma_f32_16x16x32_bf16(a, b, c, 0, 0, 0);
}
__device__ __forceinline__ void gload_lds16(const void* g, void* l) {
  __builtin_amdgcn_global_load_lds((const __attribute__((address_space(1))) void*)g,
                                   (__attribute__((address_space(3))) void*)l, 16, 0, 0);
}

// ---------------- weight conversion: Wq,Wk -> hi/lo split; Wv -> hi; bias concat
__global__ __launch_bounds__(256) void conv_w_kernel(
    const float* __restrict__ Wq, const float* __restrict__ Wk, const float* __restrict__ Wv,
    const float* __restrict__ bq, const float* __restrict__ bk,
    unsigned short* __restrict__ Wqkh, unsigned short* __restrict__ Wqkl,
    unsigned short* __restrict__ Wvh, float* __restrict__ bqk)
{
  long long tid = (long long)blockIdx.x * 256 + threadIdx.x;
  long long base = tid * 8;
  if (base < 2097152) {
    const float* src = (base < 1048576) ? (Wq + base) : (Wk + (base - 1048576));
#pragma unroll
    for (int i = 0; i < 8; ++i) {
      float f = src[i];
      unsigned short h = f2bf(f);
      Wqkh[base + i] = h;
      Wqkl[base + i] = f2bf(f - bf2f(h));
    }
  } else if (base < 3145728) {
    long long b2 = base - 2097152;
#pragma unroll
    for (int i = 0; i < 8; ++i) Wvh[b2 + i] = f2bf(Wv[b2 + i]);
  }
  if (tid < 256) {
#pragma unroll
    for (int i = 0; i < 8; ++i) {
      int j = (int)tid * 8 + i;
      bqk[j] = (j < 1024) ? bq[j] : bk[j - 1024];
    }
  }
}

// ---------------- x -> hi/lo bf16 split
__global__ __launch_bounds__(256) void conv_x_kernel(
    const float* __restrict__ xs, unsigned short* __restrict__ xh, unsigned short* __restrict__ xl)
{
  long long base = ((long long)blockIdx.x * 256 + threadIdx.x) * 8;
  float4 a = *(const float4*)(xs + base);
  float4 b = *(const float4*)(xs + base + 4);
  float v[8] = {a.x, a.y, a.z, a.w, b.x, b.y, b.z, b.w};
  short8 hv, lv;
#pragma unroll
  for (int i = 0; i < 8; ++i) {
    unsigned short h = f2bf(v[i]);
    hv[i] = (short)h;
    lv[i] = (short)f2bf(v[i] - bf2f(h));
  }
  *(short8*)(xh + base) = hv;
  *(short8*)(xl + base) = lv;
}

// ---------------- B^T-pattern GEMM: C[m][n] = sum_k A[m][k]*B[n][k] + bias
// SPLIT: 3-product hi/lo compute, hi/lo output. K fixed 1024.
template <bool SPLIT, bool BIAS_COL>
__global__ __launch_bounds__(256, 2) void gemm_bt_kernel(
    const unsigned short* __restrict__ Ah, const unsigned short* __restrict__ Al,
    const unsigned short* __restrict__ Bh, const unsigned short* __restrict__ Bl,
    const float* __restrict__ bias,
    unsigned short* __restrict__ Ch, unsigned short* __restrict__ Cl,
    int lda, int ldb, int ldc)
{
  __shared__ char lds[SPLIT ? 65536 : 32768];  // tiles: Ah@0, Bh@16K, Al@32K, Bl@48K
  const int tidx = threadIdx.x;
  const int wid = tidx >> 6, lane = tidx & 63;
  const int l = lane & 15, g = lane >> 4;
  const int wm = wid >> 1, wn = wid & 1;
  const int arow0 = blockIdx.y * 128, brow0 = blockIdx.x * 128;
  const int NT = SPLIT ? 4 : 2;

  f32x4 acc[4][4];
#pragma unroll
  for (int i = 0; i < 4; ++i)
#pragma unroll
    for (int j = 0; j < 4; ++j) acc[i][j] = (f32x4){0.f, 0.f, 0.f, 0.f};

  for (int k0 = 0; k0 < 1024; k0 += 64) {
    __syncthreads();
    for (int c = wid; c < NT * 16; c += 4) {
      const int tile = c >> 4, seg = c & 15;
      const int u = seg * 1024 + lane * 16;
      const int row = u >> 7;
      const int kb = (u & 127) ^ ((row & 7) << 4);
      const unsigned short* bp = (tile == 0) ? Ah : (tile == 1) ? Bh : (tile == 2) ? Al : Bl;
      const int r0 = (tile & 1) ? brow0 : arow0;
      const int ld = (tile & 1) ? ldb : lda;
      const char* gp = (const char*)(bp + (size_t)(r0 + row) * ld + k0) + kb;
      gload_lds16(gp, lds + tile * 16384 + seg * 1024);
    }
    __syncthreads();
#pragma unroll
    for (int ks = 0; ks < 2; ++ks) {
      short8 a_h[4], a_l[4];
#pragma unroll
      for (int mi = 0; mi < 4; ++mi) {
        const int row = wm * 64 + mi * 16 + l;
        const int off = row * 128 + ((ks * 64 + g * 16) ^ ((row & 7) << 4));
        a_h[mi] = *(const short8*)(lds + off);
        if (SPLIT) a_l[mi] = *(const short8*)(lds + 32768 + off);
      }
#pragma unroll
      for (int ni = 0; ni < 4; ++ni) {
        const int row = wn * 64 + ni * 16 + l;
        const int off = row * 128 + ((ks * 64 + g * 16) ^ ((row & 7) << 4));
        short8 b_h = *(const short8*)(lds + 16384 + off);
        short8 b_l = b_h;
        if (SPLIT) b_l = *(const short8*)(lds + 49152 + off);
#pragma unroll
        for (int mi = 0; mi < 4; ++mi) {
          acc[mi][ni] = mfma16(a_h[mi], b_h, acc[mi][ni]);
          if (SPLIT) {
            acc[mi][ni] = mfma16(a_h[mi], b_l, acc[mi][ni]);
            acc[mi][ni] = mfma16(a_l[mi], b_h, acc[mi][ni]);
          }
        }
      }
    }
  }
#pragma unroll
  for (int mi = 0; mi < 4; ++mi)
#pragma unroll
    for (int ni = 0; ni < 4; ++ni) {
      const int gcol = brow0 + wn * 64 + ni * 16 + l;
      const int grow0 = arow0 + wm * 64 + mi * 16 + g * 4;
#pragma unroll
      for (int j = 0; j < 4; ++j) {
        const int grow = grow0 + j;
        float val = acc[mi][ni][j] + (BIAS_COL ? bias[gcol] : bias[grow]);
        unsigned short h = f2bf(val);
        Ch[(size_t)grow * ldc + gcol] = h;
        if (SPLIT) Cl[(size_t)grow * ldc + gcol] = f2bf(val - bf2f(h));
      }
    }
}

// ---------------- per-window attention: scores(split) -> exact top-32 -> softmax -> P@V^T
__global__ __launch_bounds__(256, 1) void attn_kernel(
    const unsigned short* __restrict__ QKh, const unsigned short* __restrict__ QKl,
    const unsigned short* __restrict__ VT, const float* __restrict__ x,
    float* __restrict__ out, int Mc, int gr0)
{
  __shared__ char lds[65536];  // phase1: Qh@0, Kh@16K, Ql@32K, Kl@48K; then P (bf16 128x128) @0..32K
  const int tidx = threadIdx.x;
  const int wid = tidx >> 6, lane = tidx & 63;
  const int l = lane & 15, g = lane >> 4;
  const int row0 = blockIdx.x * 128;

  f32x4 acc[2][8];
#pragma unroll
  for (int i = 0; i < 2; ++i)
#pragma unroll
    for (int j = 0; j < 8; ++j) acc[i][j] = (f32x4){0.f, 0.f, 0.f, 0.f};

  for (int k0 = 0; k0 < 1024; k0 += 64) {
    __syncthreads();
    for (int c = wid; c < 64; c += 4) {
      const int tile = c >> 4, seg = c & 15;
      const int u = seg * 1024 + lane * 16;
      const int row = u >> 7;
      const int kb = (u & 127) ^ ((row & 7) << 4);
      const unsigned short* bp = (tile & 2) ? QKl : QKh;
      const int coloff = (tile & 1) ? 1024 : 0;
      const char* gp = (const char*)(bp + (size_t)(row0 + row) * 2048 + coloff + k0) + kb;
      gload_lds16(gp, lds + tile * 16384 + seg * 1024);
    }
    __syncthreads();
#pragma unroll
    for (int ks = 0; ks < 2; ++ks) {
      short8 qh[2], ql[2];
#pragma unroll
      for (int mi = 0; mi < 2; ++mi) {
        const int row = wid * 32 + mi * 16 + l;
        const int off = row * 128 + ((ks * 64 + g * 16) ^ ((row & 7) << 4));
        qh[mi] = *(const short8*)(lds + off);
        ql[mi] = *(const short8*)(lds + 32768 + off);
      }
#pragma unroll
      for (int ni = 0; ni < 8; ++ni) {
        const int row = ni * 16 + l;
        const int off = row * 128 + ((ks * 64 + g * 16) ^ ((row & 7) << 4));
        short8 kh = *(const short8*)(lds + 16384 + off);
        short8 kl = *(const short8*)(lds + 49152 + off);
#pragma unroll
        for (int mi = 0; mi < 2; ++mi) {
          acc[mi][ni] = mfma16(qh[mi], kh, acc[mi][ni]);
          acc[mi][ni] = mfma16(qh[mi], kl, acc[mi][ni]);
          acc[mi][ni] = mfma16(ql[mi], kh, acc[mi][ni]);
        }
      }
    }
  }
  __syncthreads();

  // ---- exact top-32 + softmax, in-register. Row qrow's 128 scores live in 16-lane
  // group g as acc[mi][ni][j] for ni=0..7 (col = ni*16 + l).
  const float s_scale = 1.0f / 32.0f;
#pragma unroll
  for (int mi = 0; mi < 2; ++mi) {
#pragma unroll
    for (int j = 0; j < 4; ++j) {
      const int qrow = wid * 32 + mi * 16 + g * 4 + j;
      float v0[8], vc[8];
#pragma unroll
      for (int ni = 0; ni < 8; ++ni) { v0[ni] = acc[mi][ni][j] * s_scale; vc[ni] = v0[ni]; }
      unsigned int sel = 0;
      float rmax = 0.f, ssum = 0.f;
      for (int t = 0; t < 32; ++t) {
        float bv = vc[0];
        int bi = 0;
#pragma unroll
        for (int i = 1; i < 8; ++i)
          if (vc[i] > bv) { bv = vc[i]; bi = i; }
        float cv = bv;
        int cc = (bi << 4) | l;  // cc == column index; ties -> min col (matches lax.top_k)
#pragma unroll
        for (int st = 0; st < 4; ++st) {
          const int mk = 1 << st;
          float ov = __shfl_xor(cv, mk, 16);
          int oc = __shfl_xor(cc, mk, 16);
          if (ov > cv || (ov == cv && oc < cc)) { cv = ov; cc = oc; }
        }
        if (t == 0) rmax = cv;
        ssum += __expf(cv - rmax);
        const bool win = ((cc & 15) == l);
        const int ci = cc >> 4;
#pragma unroll
        for (int i = 0; i < 8; ++i)
          if (win && ci == i) vc[i] = -__builtin_inff();
        sel |= (win ? (1u << ci) : 0u);
      }
      const float isum = 1.0f / ssum;
#pragma unroll
      for (int ni = 0; ni < 8; ++ni) {
        float p = ((sel >> ni) & 1u) ? (__expf(v0[ni] - rmax) * isum) : 0.0f;
        const int col = ni * 16 + l;
        const int addr = qrow * 256 + ((col * 2) ^ ((qrow & 7) << 4));
        *(unsigned short*)(lds + addr) = f2bf(p);
      }
    }
  }
  __syncthreads();

  // ---- phase 2: out = P @ V; wave owns h-range [wid*256, wid*256+256)
  const int wh0 = wid * 256;
  for (int hc = 0; hc < 4; ++hc) {
    f32x4 a2[8][4];
#pragma unroll
    for (int i = 0; i < 8; ++i)
#pragma unroll
      for (int j = 0; j < 4; ++j) a2[i][j] = (f32x4){0.f, 0.f, 0.f, 0.f};
#pragma unroll
    for (int ks = 0; ks < 4; ++ks) {
      short8 pa[8];
#pragma unroll
      for (int mi = 0; mi < 8; ++mi) {
        const int q = mi * 16 + l;
        const int off = q * 256 + ((ks * 64 + g * 16) ^ ((q & 7) << 4));
        pa[mi] = *(const short8*)(lds + off);
      }
#pragma unroll
      for (int ni = 0; ni < 4; ++ni) {
        const int h = wh0 + hc * 64 + ni * 16 + l;
        const short8 vb = *(const short8*)(VT + (size_t)h * Mc + row0 + ks * 32 + g * 8);
#pragma unroll
        for (int mi = 0; mi < 8; ++mi) a2[mi][ni] = mfma16(pa[mi], vb, a2[mi][ni]);
      }
    }
#pragma unroll
    for (int mi = 0; mi < 8; ++mi)
#pragma unroll
      for (int ni = 0; ni < 4; ++ni) {
        const int h = wh0 + hc * 64 + ni * 16 + l;
#pragma unroll
        for (int jj = 0; jj < 4; ++jj) {
          const int q = mi * 16 + g * 4 + jj;
          float o = a2[mi][ni][jj];
          o = (o >= 0.f) ? o : 0.01f * o;
          const size_t gi = (size_t)(gr0 + row0 + q) * 1024 + h;
          out[gi] = o + x[gi];
        }
      }
  }
}

// ---------------- row LayerNorm in-place on d_out
__global__ __launch_bounds__(256) void ln_kernel(
    float* __restrict__ out, const float* __restrict__ gamma, const float* __restrict__ beta)
{
  const int row = blockIdx.x;
  float* p = out + (size_t)row * 1024;
  const int tidx = threadIdx.x;
  float4 v = *((const float4*)p + tidx);
  float s = v.x + v.y + v.z + v.w;
  float s2 = v.x * v.x + v.y * v.y + v.z * v.z + v.w * v.w;
#pragma unroll
  for (int st = 0; st < 6; ++st) {
    const int mk = 1 << st;
    s += __shfl_xor(s, mk, 64);
    s2 += __shfl_xor(s2, mk, 64);
  }
  __shared__ float red[8];
  const int wid = tidx >> 6, lane = tidx & 63;
  if (lane == 0) { red[wid] = s; red[4 + wid] = s2; }
  __syncthreads();
  s = red[0] + red[1] + red[2] + red[3];
  s2 = red[4] + red[5] + red[6] + red[7];
  const float mu = s * (1.0f / 1024.0f);
  float var = s2 * (1.0f / 1024.0f) - mu * mu;
  var = var < 0.f ? 0.f : var;
  const float rstd = 1.0f / sqrtf(var + 1e-5f);
  float4 gm = *((const float4*)gamma + tidx);
  float4 bt = *((const float4*)beta + tidx);
  v.x = (v.x - mu) * rstd * gm.x + bt.x;
  v.y = (v.y - mu) * rstd * gm.y + bt.y;
  v.z = (v.z - mu) * rstd * gm.z + bt.z;
  v.w = (v.w - mu) * rstd * gm.w + bt.w;
  *((float4*)p + tidx) = v;
}

extern "C" void kernel_launch(void* const* d_in, const int* in_sizes, int n_in,
                              void* d_out, int out_size, void* d_ws, size_t ws_size,
                              hipStream_t stream)
{
  (void)in_sizes; (void)n_in; (void)out_size;
  const float* x = (const float*)d_in[0];
  const float* Wq = (const float*)d_in[1];
  const float* bq = (const float*)d_in[2];
  const float* Wk = (const float*)d_in[3];
  const float* bk = (const float*)d_in[4];
  const float* Wv = (const float*)d_in[5];
  const float* bv = (const float*)d_in[6];
  const float* gamma = (const float*)d_in[7];
  const float* beta = (const float*)d_in[8];
  float* out = (float*)d_out;

  char* ws = (char*)d_ws;
  size_t off = 0;
  auto alloc = [&](size_t n) {
    char* p = ws + off;
    off = (off + n + 255) & ~(size_t)255;
    return p;
  };
  unsigned short* Wqkh = (unsigned short*)alloc(2048ull * 1024 * 2);
  unsigned short* Wqkl = (unsigned short*)alloc(2048ull * 1024 * 2);
  unsigned short* Wvh = (unsigned short*)alloc(1024ull * 1024 * 2);
  float* bqk = (float*)alloc(2048 * 4);
  const size_t fixed = off;
  const size_t perBatch = 58720256ull;  // xh+xl+QKh+QKl+VT for 4096 rows
  int NB = 8;
  while (NB > 1 && fixed + (size_t)NB * perBatch + 8192 > ws_size) NB >>= 1;
  const int M = NB * 4096;
  unsigned short* xh = (unsigned short*)alloc((size_t)M * 1024 * 2);
  unsigned short* xl = (unsigned short*)alloc((size_t)M * 1024 * 2);
  unsigned short* QKh = (unsigned short*)alloc((size_t)M * 2048 * 2);
  unsigned short* QKl = (unsigned short*)alloc((size_t)M * 2048 * 2);
  unsigned short* VT = (unsigned short*)alloc((size_t)M * 1024 * 2);

  hipLaunchKernelGGL(conv_w_kernel, dim3(1536), dim3(256), 0, stream,
                     Wq, Wk, Wv, bq, bk, Wqkh, Wqkl, Wvh, bqk);
  for (int c = 0; c < 8 / NB; ++c) {
    const int r0 = c * M;
    hipLaunchKernelGGL(conv_x_kernel, dim3(M / 2), dim3(256), 0, stream,
                       x + (size_t)r0 * 1024, xh, xl);
    hipLaunchKernelGGL((gemm_bt_kernel<true, true>), dim3(16, M / 128), dim3(256), 0, stream,
                       xh, xl, Wqkh, Wqkl, bqk, QKh, QKl, 1024, 1024, 2048);
    hipLaunchKernelGGL((gemm_bt_kernel<false, false>), dim3(M / 128, 8), dim3(256), 0, stream,
                       Wvh, (const unsigned short*)nullptr, xh, (const unsigned short*)nullptr,
                       bv, VT, (unsigned short*)nullptr, 1024, 1024, M);
    hipLaunchKernelGGL(attn_kernel, dim3(M / 128), dim3(256), 0, stream,
                       QKh, QKl, VT, x, out, M, r0);
  }
  hipLaunchKernelGGL(ln_kernel, dim3(32768), dim3(256), 0, stream, out, gamma, beta);
}

// Round 2
// 970.045 us; speedup vs baseline: 1.0926x; 1.0926x over previous
//
#include <hip/hip_runtime.h>

typedef __attribute__((ext_vector_type(8))) short short8;
typedef __attribute__((ext_vector_type(4))) float f32x4;

__device__ __forceinline__ unsigned short f2bf(float f) {
  unsigned int u = __float_as_uint(f);
  u = u + 0x7FFFu + ((u >> 16) & 1u);
  return (unsigned short)(u >> 16);
}
__device__ __forceinline__ float bf2f(unsigned short b) {
  return __uint_as_float(((unsigned int)b) << 16);
}
__device__ __forceinline__ f32x4 mfma16(short8 a, short8 b, f32x4 c) {
  return __builtin_amdgcn_mfma_f32_16x16x32_bf16(a, b, c, 0, 0, 0);
}
__device__ __forceinline__ void gload_lds16(const void* g, void* l) {
  __builtin_amdgcn_global_load_lds((const __attribute__((address_space(1))) void*)g,
                                   (__attribute__((address_space(3))) void*)l, 16, 0, 0);
}
#define BAR() __builtin_amdgcn_s_barrier()
#define LGKM0() asm volatile("s_waitcnt lgkmcnt(0)" ::: "memory")
#define VM0() asm volatile("s_waitcnt vmcnt(0)" ::: "memory")
#define SCHED0() __builtin_amdgcn_sched_barrier(0)

// ---------------- weight conversion: Wq,Wk -> hi/lo split; Wv -> hi; bias concat
__global__ __launch_bounds__(256) void conv_w_kernel(
    const float* __restrict__ Wq, const float* __restrict__ Wk, const float* __restrict__ Wv,
    const float* __restrict__ bq, const float* __restrict__ bk,
    unsigned short* __restrict__ Wqkh, unsigned short* __restrict__ Wqkl,
    unsigned short* __restrict__ Wvh, float* __restrict__ bqk)
{
  long long tid = (long long)blockIdx.x * 256 + threadIdx.x;
  long long base = tid * 8;
  if (base < 2097152) {
    const float* src = (base < 1048576) ? (Wq + base) : (Wk + (base - 1048576));
#pragma unroll
    for (int i = 0; i < 8; ++i) {
      float f = src[i];
      unsigned short h = f2bf(f);
      Wqkh[base + i] = h;
      Wqkl[base + i] = f2bf(f - bf2f(h));
    }
  } else if (base < 3145728) {
    long long b2 = base - 2097152;
#pragma unroll
    for (int i = 0; i < 8; ++i) Wvh[b2 + i] = f2bf(Wv[b2 + i]);
  }
  if (tid < 256) {
#pragma unroll
    for (int i = 0; i < 8; ++i) {
      int j = (int)tid * 8 + i;
      bqk[j] = (j < 1024) ? bq[j] : bk[j - 1024];
    }
  }
}

// ---------------- x -> hi/lo bf16 split
__global__ __launch_bounds__(256) void conv_x_kernel(
    const float* __restrict__ xs, unsigned short* __restrict__ xh, unsigned short* __restrict__ xl)
{
  long long base = ((long long)blockIdx.x * 256 + threadIdx.x) * 8;
  float4 a = *(const float4*)(xs + base);
  float4 b = *(const float4*)(xs + base + 4);
  float v[8] = {a.x, a.y, a.z, a.w, b.x, b.y, b.z, b.w};
  short8 hv, lv;
#pragma unroll
  for (int i = 0; i < 8; ++i) {
    unsigned short h = f2bf(v[i]);
    hv[i] = (short)h;
    lv[i] = (short)f2bf(v[i] - bf2f(h));
  }
  *(short8*)(xh + base) = hv;
  *(short8*)(xl + base) = lv;
}

// ---------------- 256x256-tile B^T GEMM, BK=32, 8 waves, dbuf LDS, 4-phase interleave.
// C[m][n] = sum_k A[m][k]*B[n][k] + bias. SPLIT: 3-product hi/lo, hi/lo output.
// LDS granule swizzle: slot = g ^ ((row>>1)&3)  (stage source pre-permuted to match).
template <bool SPLIT, bool BIASROW, bool FASTA, int LGF>
__global__ __launch_bounds__(512, 2) void gemm256_kernel(
    const unsigned short* __restrict__ Aph, const unsigned short* __restrict__ Apl,
    const unsigned short* __restrict__ Bph, const unsigned short* __restrict__ Bpl,
    const float* __restrict__ bias,
    unsigned short* __restrict__ Ch, unsigned short* __restrict__ Cl,
    int lda, int ldb, int ldc)
{
  constexpr int TILES = SPLIT ? 4 : 2;
  constexpr int BUFS = TILES * 16384;
  constexpr int NP = TILES * 2;  // 16B-granule staging passes per K-tile
  __shared__ char lds[2 * BUFS];
  const int tid = threadIdx.x;
  const int wid = tid >> 6, lane = tid & 63;
  const int l = lane & 15, g = lane >> 4;
  const int wm = wid >> 2, wn = wid & 3;

  // bijective XCD-chunk swizzle (nwg % 8 == 0)
  const int nwg = gridDim.x;
  const int cpx = nwg >> 3;
  const int bid = (int)blockIdx.x;
  const int lin = (bid & 7) * cpx + (bid >> 3);
  const int tf = lin & ((1 << LGF) - 1), ts = lin >> LGF;
  const int ablk = FASTA ? tf : ts, bblk = FASTA ? ts : tf;
  const int arow0 = ablk * 256, brow0 = bblk * 256;

  // staging: pass p covers tile tp=p>>1, half h=p&1 (512 granules of 16B)
  const char* gsrc[NP];
  int ldsoff[NP];
#pragma unroll
  for (int p = 0; p < NP; ++p) {
    const int tp = p >> 1, h = p & 1;
    const int pi = h * 512 + wid * 64 + lane;
    const int row = pi >> 2;
    const int gl = (pi & 3) ^ ((row >> 1) & 3);
    const unsigned short* base =
        SPLIT ? ((tp == 0) ? Aph : (tp == 1) ? Apl : (tp == 2) ? Bph : Bpl)
              : ((tp == 0) ? Aph : Bph);
    const int r0 = (tp >= TILES / 2) ? brow0 : arow0;
    const int ld = (tp >= TILES / 2) ? ldb : lda;
    gsrc[p] = (const char*)(base + (size_t)(r0 + row) * ld + gl * 8);
    ldsoff[p] = tp * 16384 + h * 8192 + wid * 1024;
  }

  f32x4 acc[8][4];
#pragma unroll
  for (int i = 0; i < 8; ++i)
#pragma unroll
    for (int j = 0; j < 4; ++j) acc[i][j] = (f32x4){0.f, 0.f, 0.f, 0.f};

  // prologue: stage K-tile 0 into buf 0
#pragma unroll
  for (int p = 0; p < NP; ++p) gload_lds16(gsrc[p], &lds[ldsoff[p]]);
  VM0();
  BAR();

  const int nt = 32;  // K = 1024, BK = 32
  short8 bh[4], bl_[4];
#pragma unroll 1
  for (int t = 0; t < nt; ++t) {
    const int cur = (t & 1) ? BUFS : 0;
    const int nxt = BUFS - cur;
    const char* lc = lds + cur;
    const long long kadv = (long long)(t + 1) * 64;  // bytes per K-tile step
#pragma unroll
    for (int ph = 0; ph < 4; ++ph) {
      short8 ah[2], al_[2];
#pragma unroll
      for (int mi2 = 0; mi2 < 2; ++mi2) {
        const int row = wm * 128 + (ph * 2 + mi2) * 16 + l;
        const int off = row * 64 + ((g ^ ((row >> 1) & 3)) << 4);
        ah[mi2] = *(const short8*)(lc + off);
        if (SPLIT) al_[mi2] = *(const short8*)(lc + 16384 + off);
      }
      if (ph == 0) {
#pragma unroll
        for (int ni = 0; ni < 4; ++ni) {
          const int row = wn * 64 + ni * 16 + l;
          const int off = row * 64 + ((g ^ ((row >> 1) & 3)) << 4);
          bh[ni] = *(const short8*)(lc + (SPLIT ? 32768 : 16384) + off);
          if (SPLIT) bl_[ni] = *(const short8*)(lc + 49152 + off);
        }
      }
      if (ph < 2 && t < nt - 1) {
#pragma unroll
        for (int p = ph * (NP / 2); p < (ph + 1) * (NP / 2); ++p)
          gload_lds16(gsrc[p] + kadv, &lds[nxt + ldsoff[p]]);
      }
      BAR();
      LGKM0();
      SCHED0();
      __builtin_amdgcn_s_setprio(1);
#pragma unroll
      for (int ni = 0; ni < 4; ++ni)
#pragma unroll
        for (int mi2 = 0; mi2 < 2; ++mi2) {
          const int mi = ph * 2 + mi2;
          acc[mi][ni] = mfma16(ah[mi2], bh[ni], acc[mi][ni]);
          if (SPLIT) {
            acc[mi][ni] = mfma16(ah[mi2], bl_[ni], acc[mi][ni]);
            acc[mi][ni] = mfma16(al_[mi2], bh[ni], acc[mi][ni]);
          }
        }
      __builtin_amdgcn_s_setprio(0);
      SCHED0();
      if (ph == 3) VM0();
      BAR();
    }
  }

#pragma unroll
  for (int mi = 0; mi < 8; ++mi)
#pragma unroll
    for (int ni = 0; ni < 4; ++ni) {
      const int gcol = brow0 + wn * 64 + ni * 16 + l;
      const int grow0v = arow0 + wm * 128 + mi * 16 + g * 4;
#pragma unroll
      for (int j = 0; j < 4; ++j) {
        const int grow = grow0v + j;
        float val = acc[mi][ni][j] + (BIASROW ? bias[grow] : bias[gcol]);
        unsigned short hh = f2bf(val);
        Ch[(size_t)grow * ldc + gcol] = hh;
        if (SPLIT) Cl[(size_t)grow * ldc + gcol] = f2bf(val - bf2f(hh));
      }
    }
}

// ---------------- per-window attention: scores(split) -> exact top-32 -> softmax -> P@V^T
__global__ __launch_bounds__(256, 1) void attn_kernel(
    const unsigned short* __restrict__ QKh, const unsigned short* __restrict__ QKl,
    const unsigned short* __restrict__ VT, const float* __restrict__ x,
    float* __restrict__ out, int Mc, int gr0)
{
  __shared__ char lds[65536];  // phase1: Qh@0, Kh@16K, Ql@32K, Kl@48K; then P (bf16 128x128) @0..32K
  const int tidx = threadIdx.x;
  const int wid = tidx >> 6, lane = tidx & 63;
  const int l = lane & 15, g = lane >> 4;
  const int row0 = blockIdx.x * 128;

  f32x4 acc[2][8];
#pragma unroll
  for (int i = 0; i < 2; ++i)
#pragma unroll
    for (int j = 0; j < 8; ++j) acc[i][j] = (f32x4){0.f, 0.f, 0.f, 0.f};

  for (int k0 = 0; k0 < 1024; k0 += 64) {
    __syncthreads();
    for (int c = wid; c < 64; c += 4) {
      const int tile = c >> 4, seg = c & 15;
      const int u = seg * 1024 + lane * 16;
      const int row = u >> 7;
      const int kb = (u & 127) ^ ((row & 7) << 4);
      const unsigned short* bp = (tile & 2) ? QKl : QKh;
      const int coloff = (tile & 1) ? 1024 : 0;
      const char* gp = (const char*)(bp + (size_t)(row0 + row) * 2048 + coloff + k0) + kb;
      gload_lds16(gp, lds + tile * 16384 + seg * 1024);
    }
    __syncthreads();
#pragma unroll
    for (int ks = 0; ks < 2; ++ks) {
      short8 qh[2], ql[2];
#pragma unroll
      for (int mi = 0; mi < 2; ++mi) {
        const int row = wid * 32 + mi * 16 + l;
        const int off = row * 128 + ((ks * 64 + g * 16) ^ ((row & 7) << 4));
        qh[mi] = *(const short8*)(lds + off);
        ql[mi] = *(const short8*)(lds + 32768 + off);
      }
#pragma unroll
      for (int ni = 0; ni < 8; ++ni) {
        const int row = ni * 16 + l;
        const int off = row * 128 + ((ks * 64 + g * 16) ^ ((row & 7) << 4));
        short8 kh = *(const short8*)(lds + 16384 + off);
        short8 kl = *(const short8*)(lds + 49152 + off);
#pragma unroll
        for (int mi = 0; mi < 2; ++mi) {
          acc[mi][ni] = mfma16(qh[mi], kh, acc[mi][ni]);
          acc[mi][ni] = mfma16(qh[mi], kl, acc[mi][ni]);
          acc[mi][ni] = mfma16(ql[mi], kh, acc[mi][ni]);
        }
      }
    }
  }
  __syncthreads();

  // ---- exact top-32 + softmax, in-register. Row qrow's 128 scores live in 16-lane
  // group g as acc[mi][ni][j] for ni=0..7 (col = ni*16 + l).
  const float s_scale = 1.0f / 32.0f;
#pragma unroll
  for (int mi = 0; mi < 2; ++mi) {
#pragma unroll
    for (int j = 0; j < 4; ++j) {
      const int qrow = wid * 32 + mi * 16 + g * 4 + j;
      float v0[8], vc[8];
#pragma unroll
      for (int ni = 0; ni < 8; ++ni) { v0[ni] = acc[mi][ni][j] * s_scale; vc[ni] = v0[ni]; }
      unsigned int sel = 0;
      float rmax = 0.f, ssum = 0.f;
      for (int t = 0; t < 32; ++t) {
        float bv = vc[0];
        int bi = 0;
#pragma unroll
        for (int i = 1; i < 8; ++i)
          if (vc[i] > bv) { bv = vc[i]; bi = i; }
        float cv = bv;
        int cc = (bi << 4) | l;  // cc == column index; ties -> min col (matches lax.top_k)
#pragma unroll
        for (int st = 0; st < 4; ++st) {
          const int mk = 1 << st;
          float ov = __shfl_xor(cv, mk, 16);
          int oc = __shfl_xor(cc, mk, 16);
          if (ov > cv || (ov == cv && oc < cc)) { cv = ov; cc = oc; }
        }
        if (t == 0) rmax = cv;
        ssum += __expf(cv - rmax);
        const bool win = ((cc & 15) == l);
        const int ci = cc >> 4;
#pragma unroll
        for (int i = 0; i < 8; ++i)
          if (win && ci == i) vc[i] = -__builtin_inff();
        sel |= (win ? (1u << ci) : 0u);
      }
      const float isum = 1.0f / ssum;
#pragma unroll
      for (int ni = 0; ni < 8; ++ni) {
        float p = ((sel >> ni) & 1u) ? (__expf(v0[ni] - rmax) * isum) : 0.0f;
        const int col = ni * 16 + l;
        const int addr = qrow * 256 + ((col * 2) ^ ((qrow & 7) << 4));
        *(unsigned short*)(lds + addr) = f2bf(p);
      }
    }
  }
  __syncthreads();

  // ---- phase 2: out = P @ V; wave owns h-range [wid*256, wid*256+256)
  const int wh0 = wid * 256;
  for (int hc = 0; hc < 4; ++hc) {
    f32x4 a2[8][4];
#pragma unroll
    for (int i = 0; i < 8; ++i)
#pragma unroll
      for (int j = 0; j < 4; ++j) a2[i][j] = (f32x4){0.f, 0.f, 0.f, 0.f};
#pragma unroll
    for (int ks = 0; ks < 4; ++ks) {
      short8 pa[8];
#pragma unroll
      for (int mi = 0; mi < 8; ++mi) {
        const int q = mi * 16 + l;
        const int off = q * 256 + ((ks * 64 + g * 16) ^ ((q & 7) << 4));
        pa[mi] = *(const short8*)(lds + off);
      }
#pragma unroll
      for (int ni = 0; ni < 4; ++ni) {
        const int h = wh0 + hc * 64 + ni * 16 + l;
        const short8 vb = *(const short8*)(VT + (size_t)h * Mc + row0 + ks * 32 + g * 8);
#pragma unroll
        for (int mi = 0; mi < 8; ++mi) a2[mi][ni] = mfma16(pa[mi], vb, a2[mi][ni]);
      }
    }
#pragma unroll
    for (int mi = 0; mi < 8; ++mi)
#pragma unroll
      for (int ni = 0; ni < 4; ++ni) {
        const int h = wh0 + hc * 64 + ni * 16 + l;
#pragma unroll
        for (int jj = 0; jj < 4; ++jj) {
          const int q = mi * 16 + g * 4 + jj;
          float o = a2[mi][ni][jj];
          o = (o >= 0.f) ? o : 0.01f * o;
          const size_t gi = (size_t)(gr0 + row0 + q) * 1024 + h;
          out[gi] = o + x[gi];
        }
      }
  }
}

// ---------------- row LayerNorm in-place on d_out
__global__ __launch_bounds__(256) void ln_kernel(
    float* __restrict__ out, const float* __restrict__ gamma, const float* __restrict__ beta)
{
  const int row = blockIdx.x;
  float* p = out + (size_t)row * 1024;
  const int tidx = threadIdx.x;
  float4 v = *((const float4*)p + tidx);
  float s = v.x + v.y + v.z + v.w;
  float s2 = v.x * v.x + v.y * v.y + v.z * v.z + v.w * v.w;
#pragma unroll
  for (int st = 0; st < 6; ++st) {
    const int mk = 1 << st;
    s += __shfl_xor(s, mk, 64);
    s2 += __shfl_xor(s2, mk, 64);
  }
  __shared__ float red[8];
  const int wid = tidx >> 6, lane = tidx & 63;
  if (lane == 0) { red[wid] = s; red[4 + wid] = s2; }
  __syncthreads();
  s = red[0] + red[1] + red[2] + red[3];
  s2 = red[4] + red[5] + red[6] + red[7];
  const float mu = s * (1.0f / 1024.0f);
  float var = s2 * (1.0f / 1024.0f) - mu * mu;
  var = var < 0.f ? 0.f : var;
  const float rstd = 1.0f / sqrtf(var + 1e-5f);
  float4 gm = *((const float4*)gamma + tidx);
  float4 bt = *((const float4*)beta + tidx);
  v.x = (v.x - mu) * rstd * gm.x + bt.x;
  v.y = (v.y - mu) * rstd * gm.y + bt.y;
  v.z = (v.z - mu) * rstd * gm.z + bt.z;
  v.w = (v.w - mu) * rstd * gm.w + bt.w;
  *((float4*)p + tidx) = v;
}

extern "C" void kernel_launch(void* const* d_in, const int* in_sizes, int n_in,
                              void* d_out, int out_size, void* d_ws, size_t ws_size,
                              hipStream_t stream)
{
  (void)in_sizes; (void)n_in; (void)out_size;
  const float* x = (const float*)d_in[0];
  const float* Wq = (const float*)d_in[1];
  const float* bq = (const float*)d_in[2];
  const float* Wk = (const float*)d_in[3];
  const float* bk = (const float*)d_in[4];
  const float* Wv = (const float*)d_in[5];
  const float* bv = (const float*)d_in[6];
  const float* gamma = (const float*)d_in[7];
  const float* beta = (const float*)d_in[8];
  float* out = (float*)d_out;

  char* ws = (char*)d_ws;
  size_t off = 0;
  auto alloc = [&](size_t n) {
    char* p = ws + off;
    off = (off + n + 255) & ~(size_t)255;
    return p;
  };
  unsigned short* Wqkh = (unsigned short*)alloc(2048ull * 1024 * 2);
  unsigned short* Wqkl = (unsigned short*)alloc(2048ull * 1024 * 2);
  unsigned short* Wvh = (unsigned short*)alloc(1024ull * 1024 * 2);
  float* bqk = (float*)alloc(2048 * 4);
  const size_t fixed = off;
  const size_t perBatch = 58720256ull;  // xh+xl+QKh+QKl+VT for 4096 rows
  int NB = 8;
  while (NB > 1 && fixed + (size_t)NB * perBatch + 8192 > ws_size) NB >>= 1;
  const int M = NB * 4096;
  unsigned short* xh = (unsigned short*)alloc((size_t)M * 1024 * 2);
  unsigned short* xl = (unsigned short*)alloc((size_t)M * 1024 * 2);
  unsigned short* QKh = (unsigned short*)alloc((size_t)M * 2048 * 2);
  unsigned short* QKl = (unsigned short*)alloc((size_t)M * 2048 * 2);
  unsigned short* VT = (unsigned short*)alloc((size_t)M * 1024 * 2);

  hipLaunchKernelGGL(conv_w_kernel, dim3(1536), dim3(256), 0, stream,
                     Wq, Wk, Wv, bq, bk, Wqkh, Wqkl, Wvh, bqk);
  for (int c = 0; c < 8 / NB; ++c) {
    const int r0 = c * M;
    hipLaunchKernelGGL(conv_x_kernel, dim3(M / 2), dim3(256), 0, stream,
                       x + (size_t)r0 * 1024, xh, xl);
    // QK projection: A = xh/xl (M x 1024), B = Wqk (2048 x 1024), C = QK (M x 2048)
    hipLaunchKernelGGL((gemm256_kernel<true, false, false, 3>), dim3((M / 256) * 8), dim3(512), 0,
                       stream, xh, xl, Wqkh, Wqkl, bqk, QKh, QKl, 1024, 1024, 2048);
    // V^T: A = Wvh (1024 x 1024), B = xh (M x 1024), C = VT (1024 x M)
    hipLaunchKernelGGL((gemm256_kernel<false, true, true, 2>), dim3(4 * (M / 256)), dim3(512), 0,
                       stream, Wvh, (const unsigned short*)nullptr, xh,
                       (const unsigned short*)nullptr, bv, VT, (unsigned short*)nullptr,
                       1024, 1024, M);
    hipLaunchKernelGGL(attn_kernel, dim3(M / 128), dim3(256), 0, stream,
                       QKh, QKl, VT, x, out, M, r0);
  }
  hipLaunchKernelGGL(ln_kernel, dim3(32768), dim3(256), 0, stream, out, gamma, beta);
}

// Round 3
// 836.592 us; speedup vs baseline: 1.2669x; 1.1595x over previous
//
#include <hip/hip_runtime.h>

typedef __attribute__((ext_vector_type(8))) short short8;
typedef __attribute__((ext_vector_type(4))) float f32x4;

__device__ __forceinline__ unsigned short f2bf(float f) {
  unsigned int u = __float_as_uint(f);
  u = u + 0x7FFFu + ((u >> 16) & 1u);
  return (unsigned short)(u >> 16);
}
__device__ __forceinline__ float bf2f(unsigned short b) {
  return __uint_as_float(((unsigned int)b) << 16);
}
__device__ __forceinline__ f32x4 mfma16(short8 a, short8 b, f32x4 c) {
  return __builtin_amdgcn_mfma_f32_16x16x32_bf16(a, b, c, 0, 0, 0);
}
__device__ __forceinline__ void gload_lds16(const void* g, void* l) {
  __builtin_amdgcn_global_load_lds((const __attribute__((address_space(1))) void*)g,
                                   (__attribute__((address_space(3))) void*)l, 16, 0, 0);
}
#define BAR() __builtin_amdgcn_s_barrier()
#define LGKM0() asm volatile("s_waitcnt lgkmcnt(0)" ::: "memory")
#define VM0() asm volatile("s_waitcnt vmcnt(0)" ::: "memory")
#define SCHED0() __builtin_amdgcn_sched_barrier(0)

// 16-lane (DPP-row) max+argmin-col reduce stage. All VALU-latency, no LDS.
template <int CTRL>
__device__ __forceinline__ void dpp_step(float& cv, int& cc) {
  float ov = __int_as_float(
      __builtin_amdgcn_update_dpp(0, __float_as_int(cv), CTRL, 0xF, 0xF, false));
  int oc = __builtin_amdgcn_update_dpp(0, cc, CTRL, 0xF, 0xF, false);
  if (ov > cv || (ov == cv && oc < cc)) { cv = ov; cc = oc; }
}

// ---------------- weight conversion: Wq,Wk -> hi/lo split; Wv -> hi; bias concat
__global__ __launch_bounds__(256) void conv_w_kernel(
    const float* __restrict__ Wq, const float* __restrict__ Wk, const float* __restrict__ Wv,
    const float* __restrict__ bq, const float* __restrict__ bk,
    unsigned short* __restrict__ Wqkh, unsigned short* __restrict__ Wqkl,
    unsigned short* __restrict__ Wvh, float* __restrict__ bqk)
{
  long long tid = (long long)blockIdx.x * 256 + threadIdx.x;
  long long base = tid * 8;
  if (base < 2097152) {
    const float* src = (base < 1048576) ? (Wq + base) : (Wk + (base - 1048576));
#pragma unroll
    for (int i = 0; i < 8; ++i) {
      float f = src[i];
      unsigned short h = f2bf(f);
      Wqkh[base + i] = h;
      Wqkl[base + i] = f2bf(f - bf2f(h));
    }
  } else if (base < 3145728) {
    long long b2 = base - 2097152;
#pragma unroll
    for (int i = 0; i < 8; ++i) Wvh[b2 + i] = f2bf(Wv[b2 + i]);
  }
  if (tid < 256) {
#pragma unroll
    for (int i = 0; i < 8; ++i) {
      int j = (int)tid * 8 + i;
      bqk[j] = (j < 1024) ? bq[j] : bk[j - 1024];
    }
  }
}

// ---------------- x -> hi/lo bf16 split
__global__ __launch_bounds__(256) void conv_x_kernel(
    const float* __restrict__ xs, unsigned short* __restrict__ xh, unsigned short* __restrict__ xl)
{
  long long base = ((long long)blockIdx.x * 256 + threadIdx.x) * 8;
  float4 a = *(const float4*)(xs + base);
  float4 b = *(const float4*)(xs + base + 4);
  float v[8] = {a.x, a.y, a.z, a.w, b.x, b.y, b.z, b.w};
  short8 hv, lv;
#pragma unroll
  for (int i = 0; i < 8; ++i) {
    unsigned short h = f2bf(v[i]);
    hv[i] = (short)h;
    lv[i] = (short)f2bf(v[i] - bf2f(h));
  }
  *(short8*)(xh + base) = hv;
  *(short8*)(xl + base) = lv;
}

// ---------------- 256x256-tile B^T GEMM, BK=32, 8 waves, dbuf LDS, 4-phase interleave.
template <bool SPLIT, bool BIASROW, bool FASTA, int LGF>
__global__ __launch_bounds__(512, 2) void gemm256_kernel(
    const unsigned short* __restrict__ Aph, const unsigned short* __restrict__ Apl,
    const unsigned short* __restrict__ Bph, const unsigned short* __restrict__ Bpl,
    const float* __restrict__ bias,
    unsigned short* __restrict__ Ch, unsigned short* __restrict__ Cl,
    int lda, int ldb, int ldc)
{
  constexpr int TILES = SPLIT ? 4 : 2;
  constexpr int BUFS = TILES * 16384;
  constexpr int NP = TILES * 2;  // 16B-granule staging passes per K-tile
  __shared__ char lds[2 * BUFS];
  const int tid = threadIdx.x;
  const int wid = tid >> 6, lane = tid & 63;
  const int l = lane & 15, g = lane >> 4;
  const int wm = wid >> 2, wn = wid & 3;

  // bijective XCD-chunk swizzle (nwg % 8 == 0)
  const int nwg = gridDim.x;
  const int cpx = nwg >> 3;
  const int bid = (int)blockIdx.x;
  const int lin = (bid & 7) * cpx + (bid >> 3);
  const int tf = lin & ((1 << LGF) - 1), ts = lin >> LGF;
  const int ablk = FASTA ? tf : ts, bblk = FASTA ? ts : tf;
  const int arow0 = ablk * 256, brow0 = bblk * 256;

  // staging: pass p covers tile tp=p>>1, half h=p&1 (512 granules of 16B)
  const char* gsrc[NP];
  int ldsoff[NP];
#pragma unroll
  for (int p = 0; p < NP; ++p) {
    const int tp = p >> 1, h = p & 1;
    const int pi = h * 512 + wid * 64 + lane;
    const int row = pi >> 2;
    const int gl = (pi & 3) ^ ((row >> 1) & 3);
    const unsigned short* base =
        SPLIT ? ((tp == 0) ? Aph : (tp == 1) ? Apl : (tp == 2) ? Bph : Bpl)
              : ((tp == 0) ? Aph : Bph);
    const int r0 = (tp >= TILES / 2) ? brow0 : arow0;
    const int ld = (tp >= TILES / 2) ? ldb : lda;
    gsrc[p] = (const char*)(base + (size_t)(r0 + row) * ld + gl * 8);
    ldsoff[p] = tp * 16384 + h * 8192 + wid * 1024;
  }

  f32x4 acc[8][4];
#pragma unroll
  for (int i = 0; i < 8; ++i)
#pragma unroll
    for (int j = 0; j < 4; ++j) acc[i][j] = (f32x4){0.f, 0.f, 0.f, 0.f};

  // prologue: stage K-tile 0 into buf 0
#pragma unroll
  for (int p = 0; p < NP; ++p) gload_lds16(gsrc[p], &lds[ldsoff[p]]);
  VM0();
  BAR();

  const int nt = 32;  // K = 1024, BK = 32
  short8 bh[4], bl_[4];
#pragma unroll 1
  for (int t = 0; t < nt; ++t) {
    const int cur = (t & 1) ? BUFS : 0;
    const int nxt = BUFS - cur;
    const char* lc = lds + cur;
    const long long kadv = (long long)(t + 1) * 64;  // bytes per K-tile step
#pragma unroll
    for (int ph = 0; ph < 4; ++ph) {
      short8 ah[2], al_[2];
#pragma unroll
      for (int mi2 = 0; mi2 < 2; ++mi2) {
        const int row = wm * 128 + (ph * 2 + mi2) * 16 + l;
        const int off = row * 64 + ((g ^ ((row >> 1) & 3)) << 4);
        ah[mi2] = *(const short8*)(lc + off);
        if (SPLIT) al_[mi2] = *(const short8*)(lc + 16384 + off);
      }
      if (ph == 0) {
#pragma unroll
        for (int ni = 0; ni < 4; ++ni) {
          const int row = wn * 64 + ni * 16 + l;
          const int off = row * 64 + ((g ^ ((row >> 1) & 3)) << 4);
          bh[ni] = *(const short8*)(lc + (SPLIT ? 32768 : 16384) + off);
          if (SPLIT) bl_[ni] = *(const short8*)(lc + 49152 + off);
        }
      }
      if (ph < 2 && t < nt - 1) {
#pragma unroll
        for (int p = ph * (NP / 2); p < (ph + 1) * (NP / 2); ++p)
          gload_lds16(gsrc[p] + kadv, &lds[nxt + ldsoff[p]]);
      }
      BAR();
      LGKM0();
      SCHED0();
      __builtin_amdgcn_s_setprio(1);
#pragma unroll
      for (int ni = 0; ni < 4; ++ni)
#pragma unroll
        for (int mi2 = 0; mi2 < 2; ++mi2) {
          const int mi = ph * 2 + mi2;
          acc[mi][ni] = mfma16(ah[mi2], bh[ni], acc[mi][ni]);
          if (SPLIT) {
            acc[mi][ni] = mfma16(ah[mi2], bl_[ni], acc[mi][ni]);
            acc[mi][ni] = mfma16(al_[mi2], bh[ni], acc[mi][ni]);
          }
        }
      __builtin_amdgcn_s_setprio(0);
      SCHED0();
      if (ph == 3) VM0();
      BAR();
    }
  }

#pragma unroll
  for (int mi = 0; mi < 8; ++mi)
#pragma unroll
    for (int ni = 0; ni < 4; ++ni) {
      const int gcol = brow0 + wn * 64 + ni * 16 + l;
      const int grow0v = arow0 + wm * 128 + mi * 16 + g * 4;
#pragma unroll
      for (int j = 0; j < 4; ++j) {
        const int grow = grow0v + j;
        float val = acc[mi][ni][j] + (BIASROW ? bias[grow] : bias[gcol]);
        unsigned short hh = f2bf(val);
        Ch[(size_t)grow * ldc + gcol] = hh;
        if (SPLIT) Cl[(size_t)grow * ldc + gcol] = f2bf(val - bf2f(hh));
      }
    }
}

// ---------------- per-window attention, 64 q-rows per block (2 blocks/window):
// scores(split, via LDS-staged Q/K) -> exact top-32 (DPP, 4-row ILP) -> softmax -> P@V^T
__global__ __launch_bounds__(256, 3) void attn_kernel(
    const unsigned short* __restrict__ QKh, const unsigned short* __restrict__ QKl,
    const unsigned short* __restrict__ VT, const float* __restrict__ x,
    float* __restrict__ out, int Mc, int gr0)
{
  __shared__ char lds[49152];  // Qh@0(8K), Ql@8K(8K), Kh@16K(16K), Kl@32K(16K); P(64x128 bf16)@0..16K
  const int tidx = threadIdx.x;
  const int wid = tidx >> 6, lane = tidx & 63;
  const int l = lane & 15, g = lane >> 4;
  const int bid = (int)blockIdx.x;
  const int nblk = (int)gridDim.x;  // M/64, multiple of 16
  // siblings (same window) share bid%8 -> same XCD; windows contiguous per XCD
  const int win = (bid & 7) * (nblk >> 4) + (bid >> 4);
  const int qh = (bid >> 3) & 1;
  const int qrow0 = win * 128 + qh * 64;
  const int krow0 = win * 128;

  f32x4 acc[8];
#pragma unroll
  for (int ni = 0; ni < 8; ++ni) acc[ni] = (f32x4){0.f, 0.f, 0.f, 0.f};

  for (int k0 = 0; k0 < 1024; k0 += 64) {
    __syncthreads();
    for (int c = wid; c < 48; c += 4) {
      int tile, seglocal;
      if (c < 16) { tile = c >> 3; seglocal = c & 7; }
      else { tile = 2 + ((c - 16) >> 4); seglocal = (c - 16) & 15; }
      const int u = seglocal * 1024 + lane * 16;
      const int row = u >> 7;
      const int kb = (u & 127) ^ ((row & 7) << 4);
      const unsigned short* bp = (tile & 1) ? QKl : QKh;
      const int rb = (tile < 2) ? qrow0 : krow0;
      const int co = (tile < 2) ? 0 : 1024;
      const int tbase = (tile < 2) ? tile * 8192 : 16384 + (tile - 2) * 16384;
      const char* gp = (const char*)(bp + (size_t)(rb + row) * 2048 + co + k0) + kb;
      gload_lds16(gp, lds + tbase + seglocal * 1024);
    }
    __syncthreads();
#pragma unroll
    for (int ks = 0; ks < 2; ++ks) {
      const int qrow = wid * 16 + l;
      const int qoff = qrow * 128 + ((ks * 64 + g * 16) ^ ((qrow & 7) << 4));
      const short8 qhv = *(const short8*)(lds + qoff);
      const short8 qlv = *(const short8*)(lds + 8192 + qoff);
#pragma unroll
      for (int ni = 0; ni < 8; ++ni) {
        const int krow = ni * 16 + l;
        const int koff = krow * 128 + ((ks * 64 + g * 16) ^ ((krow & 7) << 4));
        const short8 khv = *(const short8*)(lds + 16384 + koff);
        const short8 klv = *(const short8*)(lds + 32768 + koff);
        acc[ni] = mfma16(qhv, khv, acc[ni]);
        acc[ni] = mfma16(qhv, klv, acc[ni]);
        acc[ni] = mfma16(qlv, khv, acc[ni]);
      }
    }
  }
  __syncthreads();

  // ---- exact top-32 + softmax. Thread owns rows wid*16 + g*4 + j (j=0..3);
  // row's 128 scores live across its 16-lane group: col = ni*16 + l.
  // 4 rows interleaved per t-iteration; 16-lane reduce via DPP (VALU latency).
  const float s_scale = 1.0f / 32.0f;
  float vc[4][8];
  float rmax[4], ssum[4];
  unsigned int sel[4];
#pragma unroll
  for (int j = 0; j < 4; ++j) {
#pragma unroll
    for (int ni = 0; ni < 8; ++ni) vc[j][ni] = acc[ni][j] * s_scale;
    ssum[j] = 0.f;
    sel[j] = 0u;
    rmax[j] = 0.f;
  }
#pragma unroll 1
  for (int t = 0; t < 32; ++t) {
#pragma unroll
    for (int j = 0; j < 4; ++j) {
      float bv = vc[j][0];
      int bi = 0;
#pragma unroll
      for (int i = 1; i < 8; ++i)
        if (vc[j][i] > bv) { bv = vc[j][i]; bi = i; }
      float cv = bv;
      int cc = (bi << 4) | l;  // col = (bi<<4)|l; ties -> min col (matches lax.top_k)
      dpp_step<0xB1>(cv, cc);   // quad_perm(1,0,3,2): xor 1
      dpp_step<0x4E>(cv, cc);   // quad_perm(2,3,0,1): xor 2
      dpp_step<0x141>(cv, cc);  // row_half_mirror
      dpp_step<0x140>(cv, cc);  // row_mirror
      if (t == 0) rmax[j] = cv;
      ssum[j] += __expf(cv - rmax[j]);
      const bool win_ = ((cc & 15) == l);
      const int ci = cc >> 4;
#pragma unroll
      for (int i = 0; i < 8; ++i)
        if (win_ && ci == i) vc[j][i] = -__builtin_inff();
      sel[j] |= (win_ ? (1u << ci) : 0u);
    }
  }
  // P store (bf16, swizzled) into lds[0..16K)
#pragma unroll
  for (int j = 0; j < 4; ++j) {
    const int qrow = wid * 16 + g * 4 + j;
    const float isum = 1.0f / ssum[j];
#pragma unroll
    for (int ni = 0; ni < 8; ++ni) {
      const float p =
          ((sel[j] >> ni) & 1u) ? (__expf(acc[ni][j] * s_scale - rmax[j]) * isum) : 0.0f;
      const int col = ni * 16 + l;
      const int addr = qrow * 256 + ((col * 2) ^ ((qrow & 7) << 4));
      *(unsigned short*)(lds + addr) = f2bf(p);
    }
  }
  __syncthreads();

  // ---- phase 2: out = P @ V; wave owns h-range [wid*256, wid*256+256)
  const int h0 = wid * 256;
#pragma unroll 1
  for (int hc = 0; hc < 4; ++hc) {
    f32x4 a2[4][4];
#pragma unroll
    for (int i = 0; i < 4; ++i)
#pragma unroll
      for (int j = 0; j < 4; ++j) a2[i][j] = (f32x4){0.f, 0.f, 0.f, 0.f};
#pragma unroll
    for (int ks = 0; ks < 4; ++ks) {
      short8 pa[4];
#pragma unroll
      for (int mi = 0; mi < 4; ++mi) {
        const int q = mi * 16 + l;
        const int off = q * 256 + ((ks * 64 + g * 16) ^ ((q & 7) << 4));
        pa[mi] = *(const short8*)(lds + off);
      }
#pragma unroll
      for (int ni = 0; ni < 4; ++ni) {
        const int h = h0 + hc * 64 + ni * 16 + l;
        const short8 vb = *(const short8*)(VT + (size_t)h * Mc + krow0 + ks * 32 + g * 8);
#pragma unroll
        for (int mi = 0; mi < 4; ++mi) a2[mi][ni] = mfma16(pa[mi], vb, a2[mi][ni]);
      }
    }
#pragma unroll
    for (int mi = 0; mi < 4; ++mi)
#pragma unroll
      for (int ni = 0; ni < 4; ++ni) {
        const int h = h0 + hc * 64 + ni * 16 + l;
#pragma unroll
        for (int jj = 0; jj < 4; ++jj) {
          const int q = mi * 16 + g * 4 + jj;
          float o = a2[mi][ni][jj];
          o = (o >= 0.f) ? o : 0.01f * o;
          const size_t gi = (size_t)(gr0 + qrow0 + q) * 1024 + h;
          out[gi] = o + x[gi];
        }
      }
  }
}

// ---------------- row LayerNorm in-place on d_out
__global__ __launch_bounds__(256) void ln_kernel(
    float* __restrict__ out, const float* __restrict__ gamma, const float* __restrict__ beta)
{
  const int row = blockIdx.x;
  float* p = out + (size_t)row * 1024;
  const int tidx = threadIdx.x;
  float4 v = *((const float4*)p + tidx);
  float s = v.x + v.y + v.z + v.w;
  float s2 = v.x * v.x + v.y * v.y + v.z * v.z + v.w * v.w;
#pragma unroll
  for (int st = 0; st < 6; ++st) {
    const int mk = 1 << st;
    s += __shfl_xor(s, mk, 64);
    s2 += __shfl_xor(s2, mk, 64);
  }
  __shared__ float red[8];
  const int wid = tidx >> 6, lane = tidx & 63;
  if (lane == 0) { red[wid] = s; red[4 + wid] = s2; }
  __syncthreads();
  s = red[0] + red[1] + red[2] + red[3];
  s2 = red[4] + red[5] + red[6] + red[7];
  const float mu = s * (1.0f / 1024.0f);
  float var = s2 * (1.0f / 1024.0f) - mu * mu;
  var = var < 0.f ? 0.f : var;
  const float rstd = 1.0f / sqrtf(var + 1e-5f);
  float4 gm = *((const float4*)gamma + tidx);
  float4 bt = *((const float4*)beta + tidx);
  v.x = (v.x - mu) * rstd * gm.x + bt.x;
  v.y = (v.y - mu) * rstd * gm.y + bt.y;
  v.z = (v.z - mu) * rstd * gm.z + bt.z;
  v.w = (v.w - mu) * rstd * gm.w + bt.w;
  *((float4*)p + tidx) = v;
}

extern "C" void kernel_launch(void* const* d_in, const int* in_sizes, int n_in,
                              void* d_out, int out_size, void* d_ws, size_t ws_size,
                              hipStream_t stream)
{
  (void)in_sizes; (void)n_in; (void)out_size;
  const float* x = (const float*)d_in[0];
  const float* Wq = (const float*)d_in[1];
  const float* bq = (const float*)d_in[2];
  const float* Wk = (const float*)d_in[3];
  const float* bk = (const float*)d_in[4];
  const float* Wv = (const float*)d_in[5];
  const float* bv = (const float*)d_in[6];
  const float* gamma = (const float*)d_in[7];
  const float* beta = (const float*)d_in[8];
  float* out = (float*)d_out;

  char* ws = (char*)d_ws;
  size_t off = 0;
  auto alloc = [&](size_t n) {
    char* p = ws + off;
    off = (off + n + 255) & ~(size_t)255;
    return p;
  };
  unsigned short* Wqkh = (unsigned short*)alloc(2048ull * 1024 * 2);
  unsigned short* Wqkl = (unsigned short*)alloc(2048ull * 1024 * 2);
  unsigned short* Wvh = (unsigned short*)alloc(1024ull * 1024 * 2);
  float* bqk = (float*)alloc(2048 * 4);
  const size_t fixed = off;
  const size_t perBatch = 58720256ull;  // xh+xl+QKh+QKl+VT for 4096 rows
  int NB = 8;
  while (NB > 1 && fixed + (size_t)NB * perBatch + 8192 > ws_size) NB >>= 1;
  const int M = NB * 4096;
  unsigned short* xh = (unsigned short*)alloc((size_t)M * 1024 * 2);
  unsigned short* xl = (unsigned short*)alloc((size_t)M * 1024 * 2);
  unsigned short* QKh = (unsigned short*)alloc((size_t)M * 2048 * 2);
  unsigned short* QKl = (unsigned short*)alloc((size_t)M * 2048 * 2);
  unsigned short* VT = (unsigned short*)alloc((size_t)M * 1024 * 2);

  hipLaunchKernelGGL(conv_w_kernel, dim3(1536), dim3(256), 0, stream,
                     Wq, Wk, Wv, bq, bk, Wqkh, Wqkl, Wvh, bqk);
  for (int c = 0; c < 8 / NB; ++c) {
    const int r0 = c * M;
    hipLaunchKernelGGL(conv_x_kernel, dim3(M / 2), dim3(256), 0, stream,
                       x + (size_t)r0 * 1024, xh, xl);
    // QK projection: A = xh/xl (M x 1024), B = Wqk (2048 x 1024), C = QK (M x 2048)
    hipLaunchKernelGGL((gemm256_kernel<true, false, false, 3>), dim3((M / 256) * 8), dim3(512), 0,
                       stream, xh, xl, Wqkh, Wqkl, bqk, QKh, QKl, 1024, 1024, 2048);
    // V^T: A = Wvh (1024 x 1024), B = xh (M x 1024), C = VT (1024 x M)
    hipLaunchKernelGGL((gemm256_kernel<false, true, true, 2>), dim3(4 * (M / 256)), dim3(512), 0,
                       stream, Wvh, (const unsigned short*)nullptr, xh,
                       (const unsigned short*)nullptr, bv, VT, (unsigned short*)nullptr,
                       1024, 1024, M);
    hipLaunchKernelGGL(attn_kernel, dim3(M / 64), dim3(256), 0, stream,
                       QKh, QKl, VT, x, out, M, r0);
  }
  hipLaunchKernelGGL(ln_kernel, dim3(32768), dim3(256), 0, stream, out, gamma, beta);
}

// Round 4
// 836.304 us; speedup vs baseline: 1.2673x; 1.0003x over previous
//
#include <hip/hip_runtime.h>

typedef __attribute__((ext_vector_type(8))) short short8;
typedef __attribute__((ext_vector_type(4))) float f32x4;

__device__ __forceinline__ unsigned short f2bf(float f) {
  unsigned int u = __float_as_uint(f);
  u = u + 0x7FFFu + ((u >> 16) & 1u);
  return (unsigned short)(u >> 16);
}
__device__ __forceinline__ float bf2f(unsigned short b) {
  return __uint_as_float(((unsigned int)b) << 16);
}
__device__ __forceinline__ f32x4 mfma16(short8 a, short8 b, f32x4 c) {
  return __builtin_amdgcn_mfma_f32_16x16x32_bf16(a, b, c, 0, 0, 0);
}
__device__ __forceinline__ void gload_lds16(const void* g, void* l) {
  __builtin_amdgcn_global_load_lds((const __attribute__((address_space(1))) void*)g,
                                   (__attribute__((address_space(3))) void*)l, 16, 0, 0);
}
#define BAR() __builtin_amdgcn_s_barrier()
#define LGKM0() asm volatile("s_waitcnt lgkmcnt(0)" ::: "memory")
#define VM0() asm volatile("s_waitcnt vmcnt(0)" ::: "memory")
#define VM4() asm volatile("s_waitcnt vmcnt(4)" ::: "memory")
#define SCHED0() __builtin_amdgcn_sched_barrier(0)

// 16-lane (DPP-row) max+argmin-col reduce stage. All VALU-latency, no LDS.
template <int CTRL>
__device__ __forceinline__ void dpp_step(float& cv, int& cc) {
  float ov = __int_as_float(
      __builtin_amdgcn_update_dpp(0, __float_as_int(cv), CTRL, 0xF, 0xF, false));
  int oc = __builtin_amdgcn_update_dpp(0, cc, CTRL, 0xF, 0xF, false);
  if (ov > cv || (ov == cv && oc < cc)) { cv = ov; cc = oc; }
}

// ---------------- weight conversion: Wq,Wk -> hi/lo split; Wv -> hi; bias concat
__global__ __launch_bounds__(256) void conv_w_kernel(
    const float* __restrict__ Wq, const float* __restrict__ Wk, const float* __restrict__ Wv,
    const float* __restrict__ bq, const float* __restrict__ bk,
    unsigned short* __restrict__ Wqkh, unsigned short* __restrict__ Wqkl,
    unsigned short* __restrict__ Wvh, float* __restrict__ bqk)
{
  long long tid = (long long)blockIdx.x * 256 + threadIdx.x;
  long long base = tid * 8;
  if (base < 2097152) {
    const float* src = (base < 1048576) ? (Wq + base) : (Wk + (base - 1048576));
#pragma unroll
    for (int i = 0; i < 8; ++i) {
      float f = src[i];
      unsigned short h = f2bf(f);
      Wqkh[base + i] = h;
      Wqkl[base + i] = f2bf(f - bf2f(h));
    }
  } else if (base < 3145728) {
    long long b2 = base - 2097152;
#pragma unroll
    for (int i = 0; i < 8; ++i) Wvh[b2 + i] = f2bf(Wv[b2 + i]);
  }
  if (tid < 256) {
#pragma unroll
    for (int i = 0; i < 8; ++i) {
      int j = (int)tid * 8 + i;
      bqk[j] = (j < 1024) ? bq[j] : bk[j - 1024];
    }
  }
}

// ---------------- x -> hi/lo bf16 split
__global__ __launch_bounds__(256) void conv_x_kernel(
    const float* __restrict__ xs, unsigned short* __restrict__ xh, unsigned short* __restrict__ xl)
{
  long long base = ((long long)blockIdx.x * 256 + threadIdx.x) * 8;
  float4 a = *(const float4*)(xs + base);
  float4 b = *(const float4*)(xs + base + 4);
  float v[8] = {a.x, a.y, a.z, a.w, b.x, b.y, b.z, b.w};
  short8 hv, lv;
#pragma unroll
  for (int i = 0; i < 8; ++i) {
    unsigned short h = f2bf(v[i]);
    hv[i] = (short)h;
    lv[i] = (short)f2bf(v[i] - bf2f(h));
  }
  *(short8*)(xh + base) = hv;
  *(short8*)(xl + base) = lv;
}

// ---------------- 256x256-tile B^T GEMM, BK=32, 8 waves, dbuf LDS, 4-phase interleave.
// Barriers: ph0 & ph2 (pre-MFMA lockstep) + tile boundary (VM0+BAR) = 3 per K-tile.
template <bool SPLIT, bool BIASROW, bool FASTA, int LGF>
__global__ __launch_bounds__(512, 2) void gemm256_kernel(
    const unsigned short* __restrict__ Aph, const unsigned short* __restrict__ Apl,
    const unsigned short* __restrict__ Bph, const unsigned short* __restrict__ Bpl,
    const float* __restrict__ bias,
    unsigned short* __restrict__ Ch, unsigned short* __restrict__ Cl,
    int lda, int ldb, int ldc)
{
  constexpr int TILES = SPLIT ? 4 : 2;
  constexpr int BUFS = TILES * 16384;
  constexpr int NP = TILES * 2;  // 16B-granule staging passes per K-tile
  __shared__ char lds[2 * BUFS];
  const int tid = threadIdx.x;
  const int wid = tid >> 6, lane = tid & 63;
  const int l = lane & 15, g = lane >> 4;
  const int wm = wid >> 2, wn = wid & 3;

  // bijective XCD-chunk swizzle (nwg % 8 == 0)
  const int nwg = gridDim.x;
  const int cpx = nwg >> 3;
  const int bid = (int)blockIdx.x;
  const int lin = (bid & 7) * cpx + (bid >> 3);
  const int tf = lin & ((1 << LGF) - 1), ts = lin >> LGF;
  const int ablk = FASTA ? tf : ts, bblk = FASTA ? ts : tf;
  const int arow0 = ablk * 256, brow0 = bblk * 256;

  // staging: pass p covers tile tp=p>>1, half h=p&1 (512 granules of 16B)
  const char* gsrc[NP];
  int ldsoff[NP];
#pragma unroll
  for (int p = 0; p < NP; ++p) {
    const int tp = p >> 1, h = p & 1;
    const int pi = h * 512 + wid * 64 + lane;
    const int row = pi >> 2;
    const int gl = (pi & 3) ^ ((row >> 1) & 3);
    const unsigned short* base =
        SPLIT ? ((tp == 0) ? Aph : (tp == 1) ? Apl : (tp == 2) ? Bph : Bpl)
              : ((tp == 0) ? Aph : Bph);
    const int r0 = (tp >= TILES / 2) ? brow0 : arow0;
    const int ld = (tp >= TILES / 2) ? ldb : lda;
    gsrc[p] = (const char*)(base + (size_t)(r0 + row) * ld + gl * 8);
    ldsoff[p] = tp * 16384 + h * 8192 + wid * 1024;
  }

  f32x4 acc[8][4];
#pragma unroll
  for (int i = 0; i < 8; ++i)
#pragma unroll
    for (int j = 0; j < 4; ++j) acc[i][j] = (f32x4){0.f, 0.f, 0.f, 0.f};

  // prologue: stage K-tile 0 into buf 0
#pragma unroll
  for (int p = 0; p < NP; ++p) gload_lds16(gsrc[p], &lds[ldsoff[p]]);
  VM0();
  BAR();

  const int nt = 32;  // K = 1024, BK = 32
  short8 bh[4], bl_[4];
#pragma unroll 1
  for (int t = 0; t < nt; ++t) {
    const int cur = (t & 1) ? BUFS : 0;
    const int nxt = BUFS - cur;
    const char* lc = lds + cur;
    const long long kadv = (long long)(t + 1) * 64;  // bytes per K-tile step
#pragma unroll
    for (int ph = 0; ph < 4; ++ph) {
      short8 ah[2], al_[2];
#pragma unroll
      for (int mi2 = 0; mi2 < 2; ++mi2) {
        const int row = wm * 128 + (ph * 2 + mi2) * 16 + l;
        const int off = row * 64 + ((g ^ ((row >> 1) & 3)) << 4);
        ah[mi2] = *(const short8*)(lc + off);
        if (SPLIT) al_[mi2] = *(const short8*)(lc + 16384 + off);
      }
      if (ph == 0) {
#pragma unroll
        for (int ni = 0; ni < 4; ++ni) {
          const int row = wn * 64 + ni * 16 + l;
          const int off = row * 64 + ((g ^ ((row >> 1) & 3)) << 4);
          bh[ni] = *(const short8*)(lc + (SPLIT ? 32768 : 16384) + off);
          if (SPLIT) bl_[ni] = *(const short8*)(lc + 49152 + off);
        }
      }
      if (ph < 2 && t < nt - 1) {
#pragma unroll
        for (int p = ph * (NP / 2); p < (ph + 1) * (NP / 2); ++p)
          gload_lds16(gsrc[p] + kadv, &lds[nxt + ldsoff[p]]);
      }
      if (ph == 0 || ph == 2) BAR();
      LGKM0();
      SCHED0();
      __builtin_amdgcn_s_setprio(1);
#pragma unroll
      for (int ni = 0; ni < 4; ++ni)
#pragma unroll
        for (int mi2 = 0; mi2 < 2; ++mi2) {
          const int mi = ph * 2 + mi2;
          acc[mi][ni] = mfma16(ah[mi2], bh[ni], acc[mi][ni]);
          if (SPLIT) {
            acc[mi][ni] = mfma16(ah[mi2], bl_[ni], acc[mi][ni]);
            acc[mi][ni] = mfma16(al_[mi2], bh[ni], acc[mi][ni]);
          }
        }
      __builtin_amdgcn_s_setprio(0);
      SCHED0();
      if (ph == 3) {
        VM0();
        BAR();
      }
    }
  }

#pragma unroll
  for (int mi = 0; mi < 8; ++mi)
#pragma unroll
    for (int ni = 0; ni < 4; ++ni) {
      const int gcol = brow0 + wn * 64 + ni * 16 + l;
      const int grow0v = arow0 + wm * 128 + mi * 16 + g * 4;
#pragma unroll
      for (int j = 0; j < 4; ++j) {
        const int grow = grow0v + j;
        float val = acc[mi][ni][j] + (BIASROW ? bias[grow] : bias[gcol]);
        unsigned short hh = f2bf(val);
        Ch[(size_t)grow * ldc + gcol] = hh;
        if (SPLIT) Cl[(size_t)grow * ldc + gcol] = f2bf(val - bf2f(hh));
      }
    }
}

// ---------------- per-window attention, full 128-row window per block (512 thr, 8 waves):
// triple-buffered K-step-32 staging w/ counted vmcnt(4) -> scores(split) ->
// exact top-32 (DPP) -> softmax -> P@V^T. LDS: 3x32KB staging + P 32KB @98304.
__global__ __launch_bounds__(512, 2) void attn_kernel(
    const unsigned short* __restrict__ QKh, const unsigned short* __restrict__ QKl,
    const unsigned short* __restrict__ VT, const float* __restrict__ x,
    float* __restrict__ out, int Mc, int gr0)
{
  __shared__ char lds[131072];
  const int tid = threadIdx.x;
  const int wid = tid >> 6, lane = tid & 63;
  const int l = lane & 15, g = lane >> 4;
  const int win = (int)blockIdx.x;
  const int qrow0 = win * 128;

  // staging: pass p = {Qh,Ql,Kh,Kl}, each 128 rows x 32 k (8KB); thread = one 16B granule
  const int srow = tid >> 2;
  const int sgl = (tid & 3) ^ ((srow >> 1) & 3);
  const char* gsrc[4];
#pragma unroll
  for (int p = 0; p < 4; ++p) {
    const unsigned short* bp = (p & 1) ? QKl : QKh;
    const int colbase = (p < 2) ? 0 : 1024;
    gsrc[p] = (const char*)(bp + (size_t)(qrow0 + srow) * 2048 + colbase + sgl * 8);
  }
  const int ldst = tid * 16;

  f32x4 acc[8];
#pragma unroll
  for (int ni = 0; ni < 8; ++ni) acc[ni] = (f32x4){0.f, 0.f, 0.f, 0.f};

  // prologue: stage tiles 0,1 into bufs 0,1
#pragma unroll
  for (int tt = 0; tt < 2; ++tt)
#pragma unroll
    for (int p = 0; p < 4; ++p)
      gload_lds16(gsrc[p] + tt * 64, lds + tt * 32768 + p * 8192 + ldst);
  VM4();
  BAR();

  const int qrow = wid * 16 + l;
  const int qoff = qrow * 64 + ((g ^ ((qrow >> 1) & 3)) << 4);

#pragma unroll 1
  for (int t = 0; t < 32; ++t) {
    const int cb = (t % 3) * 32768;
    if (t < 30) {
      const int nb = ((t + 2) % 3) * 32768;
      const long long adv = (long long)(t + 2) * 64;
#pragma unroll
      for (int p = 0; p < 4; ++p)
        gload_lds16(gsrc[p] + adv, lds + nb + p * 8192 + ldst);
    }
    const short8 qhv = *(const short8*)(lds + cb + qoff);
    const short8 qlv = *(const short8*)(lds + cb + 8192 + qoff);
#pragma unroll
    for (int ni = 0; ni < 8; ++ni) {
      const int krow = ni * 16 + l;
      const int koff = krow * 64 + ((g ^ ((krow >> 1) & 3)) << 4);
      const short8 khv = *(const short8*)(lds + cb + 16384 + koff);
      const short8 klv = *(const short8*)(lds + cb + 24576 + koff);
      acc[ni] = mfma16(qhv, khv, acc[ni]);
      acc[ni] = mfma16(qhv, klv, acc[ni]);
      acc[ni] = mfma16(qlv, khv, acc[ni]);
    }
    if (t < 30) { VM4(); } else { VM0(); }
    BAR();
  }

  // ---- exact top-32 + softmax. Thread owns rows wid*16 + g*4 + j (j=0..3);
  // row's 128 scores live across its 16-lane group: col = ni*16 + l.
  const float s_scale = 1.0f / 32.0f;
  float vc[4][8];
  float rmax[4], ssum[4];
  unsigned int sel[4];
#pragma unroll
  for (int j = 0; j < 4; ++j) {
#pragma unroll
    for (int ni = 0; ni < 8; ++ni) vc[j][ni] = acc[ni][j] * s_scale;
    ssum[j] = 0.f;
    sel[j] = 0u;
    rmax[j] = 0.f;
  }
#pragma unroll 1
  for (int t = 0; t < 32; ++t) {
#pragma unroll
    for (int j = 0; j < 4; ++j) {
      float bv = vc[j][0];
      int bi = 0;
#pragma unroll
      for (int i = 1; i < 8; ++i)
        if (vc[j][i] > bv) { bv = vc[j][i]; bi = i; }
      float cv = bv;
      int cc = (bi << 4) | l;  // col = (bi<<4)|l; ties -> min col (matches lax.top_k)
      dpp_step<0xB1>(cv, cc);   // quad_perm(1,0,3,2): xor 1
      dpp_step<0x4E>(cv, cc);   // quad_perm(2,3,0,1): xor 2
      dpp_step<0x141>(cv, cc);  // row_half_mirror
      dpp_step<0x140>(cv, cc);  // row_mirror
      if (t == 0) rmax[j] = cv;
      ssum[j] += __expf(cv - rmax[j]);
      const bool win_ = ((cc & 15) == l);
      const int ci = cc >> 4;
#pragma unroll
      for (int i = 0; i < 8; ++i)
        if (win_ && ci == i) vc[j][i] = -__builtin_inff();
      sel[j] |= (win_ ? (1u << ci) : 0u);
    }
  }
  // P store (bf16, swizzled) into lds[98304..131072)
#pragma unroll
  for (int j = 0; j < 4; ++j) {
    const int qr = wid * 16 + g * 4 + j;
    const float isum = 1.0f / ssum[j];
#pragma unroll
    for (int ni = 0; ni < 8; ++ni) {
      const float p =
          ((sel[j] >> ni) & 1u) ? (__expf(acc[ni][j] * s_scale - rmax[j]) * isum) : 0.0f;
      const int col = ni * 16 + l;
      const int addr = 98304 + qr * 256 + ((col * 2) ^ ((qr & 7) << 4));
      *(unsigned short*)(lds + addr) = f2bf(p);
    }
  }
  __syncthreads();

  // ---- phase 2: out = P @ V; wave owns h-range [wid*128, wid*128+128)
  const int h0 = wid * 128;
#pragma unroll 1
  for (int hc = 0; hc < 2; ++hc) {
    f32x4 a2[8][4];
#pragma unroll
    for (int i = 0; i < 8; ++i)
#pragma unroll
      for (int j = 0; j < 4; ++j) a2[i][j] = (f32x4){0.f, 0.f, 0.f, 0.f};
#pragma unroll
    for (int ks = 0; ks < 4; ++ks) {
      short8 pa[8];
#pragma unroll
      for (int mi = 0; mi < 8; ++mi) {
        const int q = mi * 16 + l;
        const int off = 98304 + q * 256 + ((ks * 64 + g * 16) ^ ((q & 7) << 4));
        pa[mi] = *(const short8*)(lds + off);
      }
#pragma unroll
      for (int ni = 0; ni < 4; ++ni) {
        const int h = h0 + hc * 64 + ni * 16 + l;
        const short8 vb = *(const short8*)(VT + (size_t)h * Mc + qrow0 + ks * 32 + g * 8);
#pragma unroll
        for (int mi = 0; mi < 8; ++mi) a2[mi][ni] = mfma16(pa[mi], vb, a2[mi][ni]);
      }
    }
#pragma unroll
    for (int mi = 0; mi < 8; ++mi)
#pragma unroll
      for (int ni = 0; ni < 4; ++ni) {
        const int h = h0 + hc * 64 + ni * 16 + l;
#pragma unroll
        for (int jj = 0; jj < 4; ++jj) {
          const int q = mi * 16 + g * 4 + jj;
          float o = a2[mi][ni][jj];
          o = (o >= 0.f) ? o : 0.01f * o;
          const size_t gi = (size_t)(gr0 + qrow0 + q) * 1024 + h;
          out[gi] = o + x[gi];
        }
      }
  }
}

// ---------------- row LayerNorm in-place on d_out
__global__ __launch_bounds__(256) void ln_kernel(
    float* __restrict__ out, const float* __restrict__ gamma, const float* __restrict__ beta)
{
  const int row = blockIdx.x;
  float* p = out + (size_t)row * 1024;
  const int tidx = threadIdx.x;
  float4 v = *((const float4*)p + tidx);
  float s = v.x + v.y + v.z + v.w;
  float s2 = v.x * v.x + v.y * v.y + v.z * v.z + v.w * v.w;
#pragma unroll
  for (int st = 0; st < 6; ++st) {
    const int mk = 1 << st;
    s += __shfl_xor(s, mk, 64);
    s2 += __shfl_xor(s2, mk, 64);
  }
  __shared__ float red[8];
  const int wid = tidx >> 6, lane = tidx & 63;
  if (lane == 0) { red[wid] = s; red[4 + wid] = s2; }
  __syncthreads();
  s = red[0] + red[1] + red[2] + red[3];
  s2 = red[4] + red[5] + red[6] + red[7];
  const float mu = s * (1.0f / 1024.0f);
  float var = s2 * (1.0f / 1024.0f) - mu * mu;
  var = var < 0.f ? 0.f : var;
  const float rstd = 1.0f / sqrtf(var + 1e-5f);
  float4 gm = *((const float4*)gamma + tidx);
  float4 bt = *((const float4*)beta + tidx);
  v.x = (v.x - mu) * rstd * gm.x + bt.x;
  v.y = (v.y - mu) * rstd * gm.y + bt.y;
  v.z = (v.z - mu) * rstd * gm.z + bt.z;
  v.w = (v.w - mu) * rstd * gm.w + bt.w;
  *((float4*)p + tidx) = v;
}

extern "C" void kernel_launch(void* const* d_in, const int* in_sizes, int n_in,
                              void* d_out, int out_size, void* d_ws, size_t ws_size,
                              hipStream_t stream)
{
  (void)in_sizes; (void)n_in; (void)out_size;
  const float* x = (const float*)d_in[0];
  const float* Wq = (const float*)d_in[1];
  const float* bq = (const float*)d_in[2];
  const float* Wk = (const float*)d_in[3];
  const float* bk = (const float*)d_in[4];
  const float* Wv = (const float*)d_in[5];
  const float* bv = (const float*)d_in[6];
  const float* gamma = (const float*)d_in[7];
  const float* beta = (const float*)d_in[8];
  float* out = (float*)d_out;

  char* ws = (char*)d_ws;
  size_t off = 0;
  auto alloc = [&](size_t n) {
    char* p = ws + off;
    off = (off + n + 255) & ~(size_t)255;
    return p;
  };
  unsigned short* Wqkh = (unsigned short*)alloc(2048ull * 1024 * 2);
  unsigned short* Wqkl = (unsigned short*)alloc(2048ull * 1024 * 2);
  unsigned short* Wvh = (unsigned short*)alloc(1024ull * 1024 * 2);
  float* bqk = (float*)alloc(2048 * 4);
  const size_t fixed = off;
  const size_t perBatch = 58720256ull;  // xh+xl+QKh+QKl+VT for 4096 rows
  int NB = 8;
  while (NB > 1 && fixed + (size_t)NB * perBatch + 8192 > ws_size) NB >>= 1;
  const int M = NB * 4096;
  unsigned short* xh = (unsigned short*)alloc((size_t)M * 1024 * 2);
  unsigned short* xl = (unsigned short*)alloc((size_t)M * 1024 * 2);
  unsigned short* QKh = (unsigned short*)alloc((size_t)M * 2048 * 2);
  unsigned short* QKl = (unsigned short*)alloc((size_t)M * 2048 * 2);
  unsigned short* VT = (unsigned short*)alloc((size_t)M * 1024 * 2);

  hipLaunchKernelGGL(conv_w_kernel, dim3(1536), dim3(256), 0, stream,
                     Wq, Wk, Wv, bq, bk, Wqkh, Wqkl, Wvh, bqk);
  for (int c = 0; c < 8 / NB; ++c) {
    const int r0 = c * M;
    hipLaunchKernelGGL(conv_x_kernel, dim3(M / 2), dim3(256), 0, stream,
                       x + (size_t)r0 * 1024, xh, xl);
    // QK projection: A = xh/xl (M x 1024), B = Wqk (2048 x 1024), C = QK (M x 2048)
    hipLaunchKernelGGL((gemm256_kernel<true, false, false, 3>), dim3((M / 256) * 8), dim3(512), 0,
                       stream, xh, xl, Wqkh, Wqkl, bqk, QKh, QKl, 1024, 1024, 2048);
    // V^T: A = Wvh (1024 x 1024), B = xh (M x 1024), C = VT (1024 x M)
    hipLaunchKernelGGL((gemm256_kernel<false, true, true, 2>), dim3(4 * (M / 256)), dim3(512), 0,
                       stream, Wvh, (const unsigned short*)nullptr, xh,
                       (const unsigned short*)nullptr, bv, VT, (unsigned short*)nullptr,
                       1024, 1024, M);
    hipLaunchKernelGGL(attn_kernel, dim3(M / 128), dim3(512), 0, stream,
                       QKh, QKl, VT, x, out, M, r0);
  }
  hipLaunchKernelGGL(ln_kernel, dim3(32768), dim3(256), 0, stream, out, gamma, beta);
}

// Round 5
// 713.338 us; speedup vs baseline: 1.4858x; 1.1724x over previous
//
#include <hip/hip_runtime.h>

typedef __attribute__((ext_vector_type(8))) short short8;
typedef __attribute__((ext_vector_type(4))) float f32x4;

__device__ __forceinline__ unsigned short f2bf(float f) {
  unsigned int u = __float_as_uint(f);
  u = u + 0x7FFFu + ((u >> 16) & 1u);
  return (unsigned short)(u >> 16);
}
__device__ __forceinline__ float bf2f(unsigned short b) {
  return __uint_as_float(((unsigned int)b) << 16);
}
__device__ __forceinline__ f32x4 mfma16(short8 a, short8 b, f32x4 c) {
  return __builtin_amdgcn_mfma_f32_16x16x32_bf16(a, b, c, 0, 0, 0);
}
__device__ __forceinline__ void gload_lds16(const void* g, void* l) {
  __builtin_amdgcn_global_load_lds((const __attribute__((address_space(1))) void*)g,
                                   (__attribute__((address_space(3))) void*)l, 16, 0, 0);
}
#define BAR() __builtin_amdgcn_s_barrier()
#define LGKM0() asm volatile("s_waitcnt lgkmcnt(0)" ::: "memory")
#define VM0() asm volatile("s_waitcnt vmcnt(0)" ::: "memory")
#define VM4() asm volatile("s_waitcnt vmcnt(4)" ::: "memory")
#define VM8() asm volatile("s_waitcnt vmcnt(8)" ::: "memory")
#define SCHED0() __builtin_amdgcn_sched_barrier(0)

// 16-lane (DPP-row) max+argmin-col reduce stage. All VALU-latency, no LDS.
template <int CTRL>
__device__ __forceinline__ void dpp_step(float& cv, int& cc) {
  float ov = __int_as_float(
      __builtin_amdgcn_update_dpp(0, __float_as_int(cv), CTRL, 0xF, 0xF, false));
  int oc = __builtin_amdgcn_update_dpp(0, cc, CTRL, 0xF, 0xF, false);
  if (ov > cv || (ov == cv && oc < cc)) { cv = ov; cc = oc; }
}

// ---------------- weight conversion: Wq,Wk -> hi/lo split; Wv -> hi; bias concat
__global__ __launch_bounds__(256) void conv_w_kernel(
    const float* __restrict__ Wq, const float* __restrict__ Wk, const float* __restrict__ Wv,
    const float* __restrict__ bq, const float* __restrict__ bk,
    unsigned short* __restrict__ Wqkh, unsigned short* __restrict__ Wqkl,
    unsigned short* __restrict__ Wvh, float* __restrict__ bqk)
{
  long long tid = (long long)blockIdx.x * 256 + threadIdx.x;
  long long base = tid * 8;
  if (base < 2097152) {
    const float* src = (base < 1048576) ? (Wq + base) : (Wk + (base - 1048576));
#pragma unroll
    for (int i = 0; i < 8; ++i) {
      float f = src[i];
      unsigned short h = f2bf(f);
      Wqkh[base + i] = h;
      Wqkl[base + i] = f2bf(f - bf2f(h));
    }
  } else if (base < 3145728) {
    long long b2 = base - 2097152;
#pragma unroll
    for (int i = 0; i < 8; ++i) Wvh[b2 + i] = f2bf(Wv[b2 + i]);
  }
  if (tid < 256) {
#pragma unroll
    for (int i = 0; i < 8; ++i) {
      int j = (int)tid * 8 + i;
      bqk[j] = (j < 1024) ? bq[j] : bk[j - 1024];
    }
  }
}

// ---------------- x -> hi/lo bf16 split
__global__ __launch_bounds__(256) void conv_x_kernel(
    const float* __restrict__ xs, unsigned short* __restrict__ xh, unsigned short* __restrict__ xl)
{
  long long base = ((long long)blockIdx.x * 256 + threadIdx.x) * 8;
  float4 a = *(const float4*)(xs + base);
  float4 b = *(const float4*)(xs + base + 4);
  float v[8] = {a.x, a.y, a.z, a.w, b.x, b.y, b.z, b.w};
  short8 hv, lv;
#pragma unroll
  for (int i = 0; i < 8; ++i) {
    unsigned short h = f2bf(v[i]);
    hv[i] = (short)h;
    lv[i] = (short)f2bf(v[i] - bf2f(h));
  }
  *(short8*)(xh + base) = hv;
  *(short8*)(xl + base) = lv;
}

// ---------------- 256x256-tile B^T GEMM, BK=32, 8 waves, dbuf LDS, 4-phase interleave.
// Barriers: ph0 & ph2 (pre-MFMA lockstep) + tile boundary (VM0+BAR) = 3 per K-tile.
template <bool SPLIT, bool BIASROW, bool FASTA, int LGF>
__global__ __launch_bounds__(512, 2) void gemm256_kernel(
    const unsigned short* __restrict__ Aph, const unsigned short* __restrict__ Apl,
    const unsigned short* __restrict__ Bph, const unsigned short* __restrict__ Bpl,
    const float* __restrict__ bias,
    unsigned short* __restrict__ Ch, unsigned short* __restrict__ Cl,
    int lda, int ldb, int ldc)
{
  constexpr int TILES = SPLIT ? 4 : 2;
  constexpr int BUFS = TILES * 16384;
  constexpr int NP = TILES * 2;  // 16B-granule staging passes per K-tile
  __shared__ char lds[2 * BUFS];
  const int tid = threadIdx.x;
  const int wid = tid >> 6, lane = tid & 63;
  const int l = lane & 15, g = lane >> 4;
  const int wm = wid >> 2, wn = wid & 3;

  // bijective XCD-chunk swizzle (nwg % 8 == 0)
  const int nwg = gridDim.x;
  const int cpx = nwg >> 3;
  const int bid = (int)blockIdx.x;
  const int lin = (bid & 7) * cpx + (bid >> 3);
  const int tf = lin & ((1 << LGF) - 1), ts = lin >> LGF;
  const int ablk = FASTA ? tf : ts, bblk = FASTA ? ts : tf;
  const int arow0 = ablk * 256, brow0 = bblk * 256;

  // staging: pass p covers tile tp=p>>1, half h=p&1 (512 granules of 16B)
  const char* gsrc[NP];
  int ldsoff[NP];
#pragma unroll
  for (int p = 0; p < NP; ++p) {
    const int tp = p >> 1, h = p & 1;
    const int pi = h * 512 + wid * 64 + lane;
    const int row = pi >> 2;
    const int gl = (pi & 3) ^ ((row >> 1) & 3);
    const unsigned short* base =
        SPLIT ? ((tp == 0) ? Aph : (tp == 1) ? Apl : (tp == 2) ? Bph : Bpl)
              : ((tp == 0) ? Aph : Bph);
    const int r0 = (tp >= TILES / 2) ? brow0 : arow0;
    const int ld = (tp >= TILES / 2) ? ldb : lda;
    gsrc[p] = (const char*)(base + (size_t)(r0 + row) * ld + gl * 8);
    ldsoff[p] = tp * 16384 + h * 8192 + wid * 1024;
  }

  f32x4 acc[8][4];
#pragma unroll
  for (int i = 0; i < 8; ++i)
#pragma unroll
    for (int j = 0; j < 4; ++j) acc[i][j] = (f32x4){0.f, 0.f, 0.f, 0.f};

  // prologue: stage K-tile 0 into buf 0
#pragma unroll
  for (int p = 0; p < NP; ++p) gload_lds16(gsrc[p], &lds[ldsoff[p]]);
  VM0();
  BAR();

  const int nt = 32;  // K = 1024, BK = 32
  short8 bh[4], bl_[4];
#pragma unroll 1
  for (int t = 0; t < nt; ++t) {
    const int cur = (t & 1) ? BUFS : 0;
    const int nxt = BUFS - cur;
    const char* lc = lds + cur;
    const long long kadv = (long long)(t + 1) * 64;  // bytes per K-tile step
#pragma unroll
    for (int ph = 0; ph < 4; ++ph) {
      short8 ah[2], al_[2];
#pragma unroll
      for (int mi2 = 0; mi2 < 2; ++mi2) {
        const int row = wm * 128 + (ph * 2 + mi2) * 16 + l;
        const int off = row * 64 + ((g ^ ((row >> 1) & 3)) << 4);
        ah[mi2] = *(const short8*)(lc + off);
        if (SPLIT) al_[mi2] = *(const short8*)(lc + 16384 + off);
      }
      if (ph == 0) {
#pragma unroll
        for (int ni = 0; ni < 4; ++ni) {
          const int row = wn * 64 + ni * 16 + l;
          const int off = row * 64 + ((g ^ ((row >> 1) & 3)) << 4);
          bh[ni] = *(const short8*)(lc + (SPLIT ? 32768 : 16384) + off);
          if (SPLIT) bl_[ni] = *(const short8*)(lc + 49152 + off);
        }
      }
      if (ph < 2 && t < nt - 1) {
#pragma unroll
        for (int p = ph * (NP / 2); p < (ph + 1) * (NP / 2); ++p)
          gload_lds16(gsrc[p] + kadv, &lds[nxt + ldsoff[p]]);
      }
      if (ph == 0 || ph == 2) BAR();
      LGKM0();
      SCHED0();
      __builtin_amdgcn_s_setprio(1);
#pragma unroll
      for (int ni = 0; ni < 4; ++ni)
#pragma unroll
        for (int mi2 = 0; mi2 < 2; ++mi2) {
          const int mi = ph * 2 + mi2;
          acc[mi][ni] = mfma16(ah[mi2], bh[ni], acc[mi][ni]);
          if (SPLIT) {
            acc[mi][ni] = mfma16(ah[mi2], bl_[ni], acc[mi][ni]);
            acc[mi][ni] = mfma16(al_[mi2], bh[ni], acc[mi][ni]);
          }
        }
      __builtin_amdgcn_s_setprio(0);
      SCHED0();
      if (ph == 3) {
        VM0();
        BAR();
      }
    }
  }

#pragma unroll
  for (int mi = 0; mi < 8; ++mi)
#pragma unroll
    for (int ni = 0; ni < 4; ++ni) {
      const int gcol = brow0 + wn * 64 + ni * 16 + l;
      const int grow0v = arow0 + wm * 128 + mi * 16 + g * 4;
#pragma unroll
      for (int j = 0; j < 4; ++j) {
        const int grow = grow0v + j;
        float val = acc[mi][ni][j] + (BIASROW ? bias[grow] : bias[gcol]);
        unsigned short hh = f2bf(val);
        Ch[(size_t)grow * ldc + gcol] = hh;
        if (SPLIT) Cl[(size_t)grow * ldc + gcol] = f2bf(val - bf2f(hh));
      }
    }
}

// ---------------- per-window attention, full 128-row window per block (512 thr, 8 waves):
// QK^T: triple-buffered K-step-32 staging w/ counted vmcnt(4) -> scores(split) ->
// exact top-32 (DPP) -> softmax -> PV with LDS-staged V chunks (8 x [128h x 128m],
// 3 bufs @0/32768/65536, depth-2 prefetch, counted vmcnt). P (bf16 128x128) @98304.
__global__ __launch_bounds__(512, 2) void attn_kernel(
    const unsigned short* __restrict__ QKh, const unsigned short* __restrict__ QKl,
    const unsigned short* __restrict__ VT, const float* __restrict__ x,
    float* __restrict__ out, int Mc, int gr0)
{
  __shared__ char lds[131072];
  const int tid = threadIdx.x;
  const int wid = tid >> 6, lane = tid & 63;
  const int l = lane & 15, g = lane >> 4;
  const int win = (int)blockIdx.x;
  const int qrow0 = win * 128;

  // QK staging: pass p = {Qh,Ql,Kh,Kl}, each 128 rows x 32 k (8KB); thread = one 16B granule
  const int srow = tid >> 2;
  const int sgl = (tid & 3) ^ ((srow >> 1) & 3);
  const char* gsrc[4];
#pragma unroll
  for (int p = 0; p < 4; ++p) {
    const unsigned short* bp = (p & 1) ? QKl : QKh;
    const int colbase = (p < 2) ? 0 : 1024;
    gsrc[p] = (const char*)(bp + (size_t)(qrow0 + srow) * 2048 + colbase + sgl * 8);
  }
  const int ldst = tid * 16;

  f32x4 acc[8];
#pragma unroll
  for (int ni = 0; ni < 8; ++ni) acc[ni] = (f32x4){0.f, 0.f, 0.f, 0.f};

  // prologue: stage tiles 0,1 into bufs 0,1
#pragma unroll
  for (int tt = 0; tt < 2; ++tt)
#pragma unroll
    for (int p = 0; p < 4; ++p)
      gload_lds16(gsrc[p] + tt * 64, lds + tt * 32768 + p * 8192 + ldst);
  VM4();
  BAR();

  const int qrow = wid * 16 + l;
  const int qoff = qrow * 64 + ((g ^ ((qrow >> 1) & 3)) << 4);

#pragma unroll 1
  for (int t = 0; t < 32; ++t) {
    const int cb = (t % 3) * 32768;
    if (t < 30) {
      const int nb = ((t + 2) % 3) * 32768;
      const long long adv = (long long)(t + 2) * 64;
#pragma unroll
      for (int p = 0; p < 4; ++p)
        gload_lds16(gsrc[p] + adv, lds + nb + p * 8192 + ldst);
    }
    const short8 qhv = *(const short8*)(lds + cb + qoff);
    const short8 qlv = *(const short8*)(lds + cb + 8192 + qoff);
#pragma unroll
    for (int ni = 0; ni < 8; ++ni) {
      const int krow = ni * 16 + l;
      const int koff = krow * 64 + ((g ^ ((krow >> 1) & 3)) << 4);
      const short8 khv = *(const short8*)(lds + cb + 16384 + koff);
      const short8 klv = *(const short8*)(lds + cb + 24576 + koff);
      acc[ni] = mfma16(qhv, khv, acc[ni]);
      acc[ni] = mfma16(qhv, klv, acc[ni]);
      acc[ni] = mfma16(qlv, khv, acc[ni]);
    }
    if (t < 30) { VM4(); } else { VM0(); }
    BAR();
  }

  // ---- V-chunk staging setup: chunk c = V^T[h: c*128..+128][m: qrow0..+128], 32 KiB.
  // granule gix in [0,2048): h = gix>>4, slot = gix&15, src col-group = slot^(h&15)
  // (linear gload_lds dest + inverse-permuted global source; reads apply the same XOR).
  const char* vsrc[4];
  int vdst[4];
#pragma unroll
  for (int p = 0; p < 4; ++p) {
    const int gix = p * 512 + tid;
    const int vh = gix >> 4, vsl = gix & 15;
    const int vmg = vsl ^ (vh & 15);
    vsrc[p] = (const char*)(VT + (size_t)vh * Mc + qrow0 + vmg * 8);
    vdst[p] = gix * 16;
  }
  const long long vstep = (long long)128 * Mc * 2;  // bytes per h-chunk

  // pre-issue V chunks 0,1 (hidden under top-k)
#pragma unroll
  for (int p = 0; p < 4; ++p) gload_lds16(vsrc[p], lds + vdst[p]);
#pragma unroll
  for (int p = 0; p < 4; ++p) gload_lds16(vsrc[p] + vstep, lds + 32768 + vdst[p]);
  SCHED0();

  // ---- exact top-32 + softmax. Thread owns rows wid*16 + g*4 + j (j=0..3);
  // row's 128 scores live across its 16-lane group: col = ni*16 + l.
  const float s_scale = 1.0f / 32.0f;
  float vc[4][8];
  float rmax[4], ssum[4];
  unsigned int sel[4];
#pragma unroll
  for (int j = 0; j < 4; ++j) {
#pragma unroll
    for (int ni = 0; ni < 8; ++ni) vc[j][ni] = acc[ni][j] * s_scale;
    ssum[j] = 0.f;
    sel[j] = 0u;
    rmax[j] = 0.f;
  }
#pragma unroll 1
  for (int t = 0; t < 32; ++t) {
#pragma unroll
    for (int j = 0; j < 4; ++j) {
      float bv = vc[j][0];
      int bi = 0;
#pragma unroll
      for (int i = 1; i < 8; ++i)
        if (vc[j][i] > bv) { bv = vc[j][i]; bi = i; }
      float cv = bv;
      int cc = (bi << 4) | l;  // col = (bi<<4)|l; ties -> min col (matches lax.top_k)
      dpp_step<0xB1>(cv, cc);   // quad_perm(1,0,3,2): xor 1
      dpp_step<0x4E>(cv, cc);   // quad_perm(2,3,0,1): xor 2
      dpp_step<0x141>(cv, cc);  // row_half_mirror
      dpp_step<0x140>(cv, cc);  // row_mirror
      if (t == 0) rmax[j] = cv;
      ssum[j] += __expf(cv - rmax[j]);
      const bool win_ = ((cc & 15) == l);
      const int ci = cc >> 4;
#pragma unroll
      for (int i = 0; i < 8; ++i)
        if (win_ && ci == i) vc[j][i] = -__builtin_inff();
      sel[j] |= (win_ ? (1u << ci) : 0u);
    }
  }
  // P store (bf16, swizzled) into lds[98304..131072)
#pragma unroll
  for (int j = 0; j < 4; ++j) {
    const int qr = wid * 16 + g * 4 + j;
    const float isum = 1.0f / ssum[j];
#pragma unroll
    for (int ni = 0; ni < 8; ++ni) {
      const float p =
          ((sel[j] >> ni) & 1u) ? (__expf(acc[ni][j] * s_scale - rmax[j]) * isum) : 0.0f;
      const int col = ni * 16 + l;
      const int addr = 98304 + qr * 256 + ((col * 2) ^ ((qr & 7) << 4));
      *(unsigned short*)(lds + addr) = f2bf(p);
    }
  }
  __syncthreads();

  // ---- phase 2: out = P @ V over 8 h-chunks of 128; wave owns 16 h per chunk.
#pragma unroll 1
  for (int hc = 0; hc < 8; ++hc) {
    BAR();  // all waves done reading the buffer about to be overwritten
    if (hc < 6) {
      const long long cadv = (long long)(hc + 2) * vstep;
      const int nb = ((hc + 2) % 3) * 32768;
#pragma unroll
      for (int p = 0; p < 4; ++p) gload_lds16(vsrc[p] + cadv, lds + nb + vdst[p]);
    }
    if (hc < 6) { VM8(); } else if (hc == 6) { VM4(); } else { VM0(); }
    BAR();
    const char* vbb = lds + (hc % 3) * 32768;
    f32x4 a2[8];
#pragma unroll
    for (int i = 0; i < 8; ++i) a2[i] = (f32x4){0.f, 0.f, 0.f, 0.f};
#pragma unroll
    for (int ks = 0; ks < 4; ++ks) {
      short8 pa[8];
#pragma unroll
      for (int mi = 0; mi < 8; ++mi) {
        const int q = mi * 16 + l;
        pa[mi] =
            *(const short8*)(lds + 98304 + q * 256 + ((ks * 64 + g * 16) ^ ((q & 7) << 4)));
      }
      const int hl = wid * 16 + l;
      const short8 vb = *(const short8*)(vbb + hl * 256 + ((ks * 64 + g * 16) ^ (l << 4)));
#pragma unroll
      for (int mi = 0; mi < 8; ++mi) a2[mi] = mfma16(pa[mi], vb, a2[mi]);
    }
    const int h = hc * 128 + wid * 16 + l;
#pragma unroll
    for (int mi = 0; mi < 8; ++mi)
#pragma unroll
      for (int jj = 0; jj < 4; ++jj) {
        const int q = mi * 16 + g * 4 + jj;
        float o = a2[mi][jj];
        o = (o >= 0.f) ? o : 0.01f * o;
        const size_t gi = (size_t)(gr0 + qrow0 + q) * 1024 + h;
        out[gi] = o + x[gi];
      }
  }
}

// ---------------- row LayerNorm in-place on d_out
__global__ __launch_bounds__(256) void ln_kernel(
    float* __restrict__ out, const float* __restrict__ gamma, const float* __restrict__ beta)
{
  const int row = blockIdx.x;
  float* p = out + (size_t)row * 1024;
  const int tidx = threadIdx.x;
  float4 v = *((const float4*)p + tidx);
  float s = v.x + v.y + v.z + v.w;
  float s2 = v.x * v.x + v.y * v.y + v.z * v.z + v.w * v.w;
#pragma unroll
  for (int st = 0; st < 6; ++st) {
    const int mk = 1 << st;
    s += __shfl_xor(s, mk, 64);
    s2 += __shfl_xor(s2, mk, 64);
  }
  __shared__ float red[8];
  const int wid = tidx >> 6, lane = tidx & 63;
  if (lane == 0) { red[wid] = s; red[4 + wid] = s2; }
  __syncthreads();
  s = red[0] + red[1] + red[2] + red[3];
  s2 = red[4] + red[5] + red[6] + red[7];
  const float mu = s * (1.0f / 1024.0f);
  float var = s2 * (1.0f / 1024.0f) - mu * mu;
  var = var < 0.f ? 0.f : var;
  const float rstd = 1.0f / sqrtf(var + 1e-5f);
  float4 gm = *((const float4*)gamma + tidx);
  float4 bt = *((const float4*)beta + tidx);
  v.x = (v.x - mu) * rstd * gm.x + bt.x;
  v.y = (v.y - mu) * rstd * gm.y + bt.y;
  v.z = (v.z - mu) * rstd * gm.z + bt.z;
  v.w = (v.w - mu) * rstd * gm.w + bt.w;
  *((float4*)p + tidx) = v;
}

extern "C" void kernel_launch(void* const* d_in, const int* in_sizes, int n_in,
                              void* d_out, int out_size, void* d_ws, size_t ws_size,
                              hipStream_t stream)
{
  (void)in_sizes; (void)n_in; (void)out_size;
  const float* x = (const float*)d_in[0];
  const float* Wq = (const float*)d_in[1];
  const float* bq = (const float*)d_in[2];
  const float* Wk = (const float*)d_in[3];
  const float* bk = (const float*)d_in[4];
  const float* Wv = (const float*)d_in[5];
  const float* bv = (const float*)d_in[6];
  const float* gamma = (const float*)d_in[7];
  const float* beta = (const float*)d_in[8];
  float* out = (float*)d_out;

  char* ws = (char*)d_ws;
  size_t off = 0;
  auto alloc = [&](size_t n) {
    char* p = ws + off;
    off = (off + n + 255) & ~(size_t)255;
    return p;
  };
  unsigned short* Wqkh = (unsigned short*)alloc(2048ull * 1024 * 2);
  unsigned short* Wqkl = (unsigned short*)alloc(2048ull * 1024 * 2);
  unsigned short* Wvh = (unsigned short*)alloc(1024ull * 1024 * 2);
  float* bqk = (float*)alloc(2048 * 4);
  const size_t fixed = off;
  const size_t perBatch = 58720256ull;  // xh+xl+QKh+QKl+VT for 4096 rows
  int NB = 8;
  while (NB > 1 && fixed + (size_t)NB * perBatch + 8192 > ws_size) NB >>= 1;
  const int M = NB * 4096;
  unsigned short* xh = (unsigned short*)alloc((size_t)M * 1024 * 2);
  unsigned short* xl = (unsigned short*)alloc((size_t)M * 1024 * 2);
  unsigned short* QKh = (unsigned short*)alloc((size_t)M * 2048 * 2);
  unsigned short* QKl = (unsigned short*)alloc((size_t)M * 2048 * 2);
  unsigned short* VT = (unsigned short*)alloc((size_t)M * 1024 * 2);

  hipLaunchKernelGGL(conv_w_kernel, dim3(1536), dim3(256), 0, stream,
                     Wq, Wk, Wv, bq, bk, Wqkh, Wqkl, Wvh, bqk);
  for (int c = 0; c < 8 / NB; ++c) {
    const int r0 = c * M;
    hipLaunchKernelGGL(conv_x_kernel, dim3(M / 2), dim3(256), 0, stream,
                       x + (size_t)r0 * 1024, xh, xl);
    // QK projection: A = xh/xl (M x 1024), B = Wqk (2048 x 1024), C = QK (M x 2048)
    hipLaunchKernelGGL((gemm256_kernel<true, false, false, 3>), dim3((M / 256) * 8), dim3(512), 0,
                       stream, xh, xl, Wqkh, Wqkl, bqk, QKh, QKl, 1024, 1024, 2048);
    // V^T: A = Wvh (1024 x 1024), B = xh (M x 1024), C = VT (1024 x M)
    hipLaunchKernelGGL((gemm256_kernel<false, true, true, 2>), dim3(4 * (M / 256)), dim3(512), 0,
                       stream, Wvh, (const unsigned short*)nullptr, xh,
                       (const unsigned short*)nullptr, bv, VT, (unsigned short*)nullptr,
                       1024, 1024, M);
    hipLaunchKernelGGL(attn_kernel, dim3(M / 128), dim3(512), 0, stream,
                       QKh, QKl, VT, x, out, M, r0);
  }
  hipLaunchKernelGGL(ln_kernel, dim3(32768), dim3(256), 0, stream, out, gamma, beta);
}

// Round 6
// 711.634 us; speedup vs baseline: 1.4893x; 1.0024x over previous
//
#include <hip/hip_runtime.h>

typedef __attribute__((ext_vector_type(8))) short short8;
typedef __attribute__((ext_vector_type(4))) float f32x4;

__device__ __forceinline__ unsigned short f2bf(float f) {
  unsigned int u = __float_as_uint(f);
  u = u + 0x7FFFu + ((u >> 16) & 1u);
  return (unsigned short)(u >> 16);
}
__device__ __forceinline__ float bf2f(unsigned short b) {
  return __uint_as_float(((unsigned int)b) << 16);
}
__device__ __forceinline__ f32x4 mfma16(short8 a, short8 b, f32x4 c) {
  return __builtin_amdgcn_mfma_f32_16x16x32_bf16(a, b, c, 0, 0, 0);
}
__device__ __forceinline__ void gload_lds16(const void* g, void* l) {
  __builtin_amdgcn_global_load_lds((const __attribute__((address_space(1))) void*)g,
                                   (__attribute__((address_space(3))) void*)l, 16, 0, 0);
}
#define BAR() __builtin_amdgcn_s_barrier()
#define VM0() asm volatile("s_waitcnt vmcnt(0)" ::: "memory")
#define VM4() asm volatile("s_waitcnt vmcnt(4)" ::: "memory")
#define VM8() asm volatile("s_waitcnt vmcnt(8)" ::: "memory")
#define SCHED0() __builtin_amdgcn_sched_barrier(0)

// 16-lane (DPP-row) max+argmin-col reduce stage. All VALU-latency, no LDS.
template <int CTRL>
__device__ __forceinline__ void dpp_step(float& cv, int& cc) {
  float ov = __int_as_float(
      __builtin_amdgcn_update_dpp(0, __float_as_int(cv), CTRL, 0xF, 0xF, false));
  int oc = __builtin_amdgcn_update_dpp(0, cc, CTRL, 0xF, 0xF, false);
  if (ov > cv || (ov == cv && oc < cc)) { cv = ov; cc = oc; }
}

// ---------------- weight conversion: Wq,Wk -> hi/lo split; Wv -> hi; bias concat
__global__ __launch_bounds__(256) void conv_w_kernel(
    const float* __restrict__ Wq, const float* __restrict__ Wk, const float* __restrict__ Wv,
    const float* __restrict__ bq, const float* __restrict__ bk,
    unsigned short* __restrict__ Wqkh, unsigned short* __restrict__ Wqkl,
    unsigned short* __restrict__ Wvh, float* __restrict__ bqk)
{
  long long tid = (long long)blockIdx.x * 256 + threadIdx.x;
  long long base = tid * 8;
  if (base < 2097152) {
    const float* src = (base < 1048576) ? (Wq + base) : (Wk + (base - 1048576));
#pragma unroll
    for (int i = 0; i < 8; ++i) {
      float f = src[i];
      unsigned short h = f2bf(f);
      Wqkh[base + i] = h;
      Wqkl[base + i] = f2bf(f - bf2f(h));
    }
  } else if (base < 3145728) {
    long long b2 = base - 2097152;
#pragma unroll
    for (int i = 0; i < 8; ++i) Wvh[b2 + i] = f2bf(Wv[b2 + i]);
  }
  if (tid < 256) {
#pragma unroll
    for (int i = 0; i < 8; ++i) {
      int j = (int)tid * 8 + i;
      bqk[j] = (j < 1024) ? bq[j] : bk[j - 1024];
    }
  }
}

// ---------------- x -> hi/lo bf16 split
__global__ __launch_bounds__(256) void conv_x_kernel(
    const float* __restrict__ xs, unsigned short* __restrict__ xh, unsigned short* __restrict__ xl)
{
  long long base = ((long long)blockIdx.x * 256 + threadIdx.x) * 8;
  float4 a = *(const float4*)(xs + base);
  float4 b = *(const float4*)(xs + base + 4);
  float v[8] = {a.x, a.y, a.z, a.w, b.x, b.y, b.z, b.w};
  short8 hv, lv;
#pragma unroll
  for (int i = 0; i < 8; ++i) {
    unsigned short h = f2bf(v[i]);
    hv[i] = (short)h;
    lv[i] = (short)f2bf(v[i] - bf2f(h));
  }
  *(short8*)(xh + base) = hv;
  *(short8*)(xl + base) = lv;
}

// ---------------- 256x256-tile B^T GEMM, BK=32, 8 waves, dbuf LDS.
// Flat compiler-scheduled tile body; ONE barrier per K-tile (VM0+BAR at tile end,
// which is the only correctness requirement: each wave drains its own
// global_load_lds, then the barrier makes all waves' staging visible).
template <bool SPLIT, bool BIASROW, bool FASTA, int LGF>
__global__ __launch_bounds__(512, 2) void gemm256_kernel(
    const unsigned short* __restrict__ Aph, const unsigned short* __restrict__ Apl,
    const unsigned short* __restrict__ Bph, const unsigned short* __restrict__ Bpl,
    const float* __restrict__ bias,
    unsigned short* __restrict__ Ch, unsigned short* __restrict__ Cl,
    int lda, int ldb, int ldc)
{
  constexpr int TILES = SPLIT ? 4 : 2;
  constexpr int BUFS = TILES * 16384;
  constexpr int NP = TILES * 2;  // 16B-granule staging passes per K-tile
  __shared__ char lds[2 * BUFS];
  const int tid = threadIdx.x;
  const int wid = tid >> 6, lane = tid & 63;
  const int l = lane & 15, g = lane >> 4;
  const int wm = wid >> 2, wn = wid & 3;

  // bijective XCD-chunk swizzle (nwg % 8 == 0)
  const int nwg = gridDim.x;
  const int cpx = nwg >> 3;
  const int bid = (int)blockIdx.x;
  const int lin = (bid & 7) * cpx + (bid >> 3);
  const int tf = lin & ((1 << LGF) - 1), ts = lin >> LGF;
  const int ablk = FASTA ? tf : ts, bblk = FASTA ? ts : tf;
  const int arow0 = ablk * 256, brow0 = bblk * 256;

  // staging: pass p covers tile tp=p>>1, half h=p&1 (512 granules of 16B)
  const char* gsrc[NP];
  int ldsoff[NP];
#pragma unroll
  for (int p = 0; p < NP; ++p) {
    const int tp = p >> 1, h = p & 1;
    const int pi = h * 512 + wid * 64 + lane;
    const int row = pi >> 2;
    const int gl = (pi & 3) ^ ((row >> 1) & 3);
    const unsigned short* base =
        SPLIT ? ((tp == 0) ? Aph : (tp == 1) ? Apl : (tp == 2) ? Bph : Bpl)
              : ((tp == 0) ? Aph : Bph);
    const int r0 = (tp >= TILES / 2) ? brow0 : arow0;
    const int ld = (tp >= TILES / 2) ? ldb : lda;
    gsrc[p] = (const char*)(base + (size_t)(r0 + row) * ld + gl * 8);
    ldsoff[p] = tp * 16384 + h * 8192 + wid * 1024;
  }

  f32x4 acc[8][4];
#pragma unroll
  for (int i = 0; i < 8; ++i)
#pragma unroll
    for (int j = 0; j < 4; ++j) acc[i][j] = (f32x4){0.f, 0.f, 0.f, 0.f};

  // prologue: stage K-tile 0 into buf 0
#pragma unroll
  for (int p = 0; p < NP; ++p) gload_lds16(gsrc[p], &lds[ldsoff[p]]);
  VM0();
  BAR();

  const int nt = 32;  // K = 1024, BK = 32
#pragma unroll 1
  for (int t = 0; t < nt; ++t) {
    const int cur = (t & 1) ? BUFS : 0;
    const int nxt = BUFS - cur;
    const char* lc = lds + cur;
    const long long kadv = (long long)(t + 1) * 64;  // bytes per K-tile step

    // issue next tile's staging first (in-flight across the whole tile body)
    if (t < nt - 1) {
#pragma unroll
      for (int p = 0; p < NP; ++p) gload_lds16(gsrc[p] + kadv, &lds[nxt + ldsoff[p]]);
    }

    // flat compute on cur; compiler schedules ds_reads/MFMA interleave freely.
    short8 bh[4], bl_[4];
#pragma unroll
    for (int ni = 0; ni < 4; ++ni) {
      const int row = wn * 64 + ni * 16 + l;
      const int off = row * 64 + ((g ^ ((row >> 1) & 3)) << 4);
      bh[ni] = *(const short8*)(lc + (SPLIT ? 32768 : 16384) + off);
      if (SPLIT) bl_[ni] = *(const short8*)(lc + 49152 + off);
    }
#pragma unroll
    for (int mi = 0; mi < 8; ++mi) {
      const int row = wm * 128 + mi * 16 + l;
      const int off = row * 64 + ((g ^ ((row >> 1) & 3)) << 4);
      short8 ah = *(const short8*)(lc + off);
      short8 al_ = ah;
      if (SPLIT) al_ = *(const short8*)(lc + 16384 + off);
#pragma unroll
      for (int ni = 0; ni < 4; ++ni) {
        acc[mi][ni] = mfma16(ah, bh[ni], acc[mi][ni]);
        if (SPLIT) {
          acc[mi][ni] = mfma16(ah, bl_[ni], acc[mi][ni]);
          acc[mi][ni] = mfma16(al_, bh[ni], acc[mi][ni]);
        }
      }
    }

    VM0();  // own staging loads done; barrier makes all waves' staging visible
    BAR();
  }

#pragma unroll
  for (int mi = 0; mi < 8; ++mi)
#pragma unroll
    for (int ni = 0; ni < 4; ++ni) {
      const int gcol = brow0 + wn * 64 + ni * 16 + l;
      const int grow0v = arow0 + wm * 128 + mi * 16 + g * 4;
#pragma unroll
      for (int j = 0; j < 4; ++j) {
        const int grow = grow0v + j;
        float val = acc[mi][ni][j] + (BIASROW ? bias[grow] : bias[gcol]);
        unsigned short hh = f2bf(val);
        Ch[(size_t)grow * ldc + gcol] = hh;
        if (SPLIT) Cl[(size_t)grow * ldc + gcol] = f2bf(val - bf2f(hh));
      }
    }
}

// ---------------- per-window attention, full 128-row window per block (512 thr, 8 waves):
// QK^T: triple-buffered K-step-32 staging w/ counted vmcnt(4) -> scores(split) ->
// exact top-32 (DPP) -> softmax -> PV with LDS-staged V chunks (8 x [128h x 128m],
// 3 bufs @0/32768/65536, depth-2 prefetch, counted vmcnt). P (bf16 128x128) @98304.
__global__ __launch_bounds__(512, 2) void attn_kernel(
    const unsigned short* __restrict__ QKh, const unsigned short* __restrict__ QKl,
    const unsigned short* __restrict__ VT, const float* __restrict__ x,
    float* __restrict__ out, int Mc, int gr0)
{
  __shared__ char lds[131072];
  const int tid = threadIdx.x;
  const int wid = tid >> 6, lane = tid & 63;
  const int l = lane & 15, g = lane >> 4;
  const int win = (int)blockIdx.x;
  const int qrow0 = win * 128;

  // QK staging: pass p = {Qh,Ql,Kh,Kl}, each 128 rows x 32 k (8KB); thread = one 16B granule
  const int srow = tid >> 2;
  const int sgl = (tid & 3) ^ ((srow >> 1) & 3);
  const char* gsrc[4];
#pragma unroll
  for (int p = 0; p < 4; ++p) {
    const unsigned short* bp = (p & 1) ? QKl : QKh;
    const int colbase = (p < 2) ? 0 : 1024;
    gsrc[p] = (const char*)(bp + (size_t)(qrow0 + srow) * 2048 + colbase + sgl * 8);
  }
  const int ldst = tid * 16;

  f32x4 acc[8];
#pragma unroll
  for (int ni = 0; ni < 8; ++ni) acc[ni] = (f32x4){0.f, 0.f, 0.f, 0.f};

  // prologue: stage tiles 0,1 into bufs 0,1
#pragma unroll
  for (int tt = 0; tt < 2; ++tt)
#pragma unroll
    for (int p = 0; p < 4; ++p)
      gload_lds16(gsrc[p] + tt * 64, lds + tt * 32768 + p * 8192 + ldst);
  VM4();
  BAR();

  const int qrow = wid * 16 + l;
  const int qoff = qrow * 64 + ((g ^ ((qrow >> 1) & 3)) << 4);

#pragma unroll 1
  for (int t = 0; t < 32; ++t) {
    const int cb = (t % 3) * 32768;
    if (t < 30) {
      const int nb = ((t + 2) % 3) * 32768;
      const long long adv = (long long)(t + 2) * 64;
#pragma unroll
      for (int p = 0; p < 4; ++p)
        gload_lds16(gsrc[p] + adv, lds + nb + p * 8192 + ldst);
    }
    const short8 qhv = *(const short8*)(lds + cb + qoff);
    const short8 qlv = *(const short8*)(lds + cb + 8192 + qoff);
#pragma unroll
    for (int ni = 0; ni < 8; ++ni) {
      const int krow = ni * 16 + l;
      const int koff = krow * 64 + ((g ^ ((krow >> 1) & 3)) << 4);
      const short8 khv = *(const short8*)(lds + cb + 16384 + koff);
      const short8 klv = *(const short8*)(lds + cb + 24576 + koff);
      acc[ni] = mfma16(qhv, khv, acc[ni]);
      acc[ni] = mfma16(qhv, klv, acc[ni]);
      acc[ni] = mfma16(qlv, khv, acc[ni]);
    }
    if (t < 30) { VM4(); } else { VM0(); }
    BAR();
  }

  // ---- V-chunk staging setup: chunk c = V^T[h: c*128..+128][m: qrow0..+128], 32 KiB.
  // granule gix in [0,2048): h = gix>>4, slot = gix&15, src col-group = slot^(h&15)
  // (linear gload_lds dest + inverse-permuted global source; reads apply the same XOR).
  const char* vsrc[4];
  int vdst[4];
#pragma unroll
  for (int p = 0; p < 4; ++p) {
    const int gix = p * 512 + tid;
    const int vh = gix >> 4, vsl = gix & 15;
    const int vmg = vsl ^ (vh & 15);
    vsrc[p] = (const char*)(VT + (size_t)vh * Mc + qrow0 + vmg * 8);
    vdst[p] = gix * 16;
  }
  const long long vstep = (long long)128 * Mc * 2;  // bytes per h-chunk

  // pre-issue V chunks 0,1 (hidden under top-k)
#pragma unroll
  for (int p = 0; p < 4; ++p) gload_lds16(vsrc[p], lds + vdst[p]);
#pragma unroll
  for (int p = 0; p < 4; ++p) gload_lds16(vsrc[p] + vstep, lds + 32768 + vdst[p]);
  SCHED0();

  // ---- exact top-32 + softmax. Thread owns rows wid*16 + g*4 + j (j=0..3);
  // row's 128 scores live across its 16-lane group: col = ni*16 + l.
  const float s_scale = 1.0f / 32.0f;
  float vc[4][8];
  float rmax[4], ssum[4];
  unsigned int sel[4];
#pragma unroll
  for (int j = 0; j < 4; ++j) {
#pragma unroll
    for (int ni = 0; ni < 8; ++ni) vc[j][ni] = acc[ni][j] * s_scale;
    ssum[j] = 0.f;
    sel[j] = 0u;
    rmax[j] = 0.f;
  }
#pragma unroll 1
  for (int t = 0; t < 32; ++t) {
#pragma unroll
    for (int j = 0; j < 4; ++j) {
      float bv = vc[j][0];
      int bi = 0;
#pragma unroll
      for (int i = 1; i < 8; ++i)
        if (vc[j][i] > bv) { bv = vc[j][i]; bi = i; }
      float cv = bv;
      int cc = (bi << 4) | l;  // col = (bi<<4)|l; ties -> min col (matches lax.top_k)
      dpp_step<0xB1>(cv, cc);   // quad_perm(1,0,3,2): xor 1
      dpp_step<0x4E>(cv, cc);   // quad_perm(2,3,0,1): xor 2
      dpp_step<0x141>(cv, cc);  // row_half_mirror
      dpp_step<0x140>(cv, cc);  // row_mirror
      if (t == 0) rmax[j] = cv;
      ssum[j] += __expf(cv - rmax[j]);
      const bool win_ = ((cc & 15) == l);
      const int ci = cc >> 4;
#pragma unroll
      for (int i = 0; i < 8; ++i)
        if (win_ && ci == i) vc[j][i] = -__builtin_inff();
      sel[j] |= (win_ ? (1u << ci) : 0u);
    }
  }
  // P store (bf16, swizzled) into lds[98304..131072)
#pragma unroll
  for (int j = 0; j < 4; ++j) {
    const int qr = wid * 16 + g * 4 + j;
    const float isum = 1.0f / ssum[j];
#pragma unroll
    for (int ni = 0; ni < 8; ++ni) {
      const float p =
          ((sel[j] >> ni) & 1u) ? (__expf(acc[ni][j] * s_scale - rmax[j]) * isum) : 0.0f;
      const int col = ni * 16 + l;
      const int addr = 98304 + qr * 256 + ((col * 2) ^ ((qr & 7) << 4));
      *(unsigned short*)(lds + addr) = f2bf(p);
    }
  }
  __syncthreads();

  // ---- phase 2: out = P @ V over 8 h-chunks of 128; wave owns 16 h per chunk.
#pragma unroll 1
  for (int hc = 0; hc < 8; ++hc) {
    BAR();  // all waves done reading the buffer about to be overwritten
    if (hc < 6) {
      const long long cadv = (long long)(hc + 2) * vstep;
      const int nb = ((hc + 2) % 3) * 32768;
#pragma unroll
      for (int p = 0; p < 4; ++p) gload_lds16(vsrc[p] + cadv, lds + nb + vdst[p]);
    }
    if (hc < 6) { VM8(); } else if (hc == 6) { VM4(); } else { VM0(); }
    BAR();
    const char* vbb = lds + (hc % 3) * 32768;
    f32x4 a2[8];
#pragma unroll
    for (int i = 0; i < 8; ++i) a2[i] = (f32x4){0.f, 0.f, 0.f, 0.f};
#pragma unroll
    for (int ks = 0; ks < 4; ++ks) {
      short8 pa[8];
#pragma unroll
      for (int mi = 0; mi < 8; ++mi) {
        const int q = mi * 16 + l;
        pa[mi] =
            *(const short8*)(lds + 98304 + q * 256 + ((ks * 64 + g * 16) ^ ((q & 7) << 4)));
      }
      const int hl = wid * 16 + l;
      const short8 vb = *(const short8*)(vbb + hl * 256 + ((ks * 64 + g * 16) ^ (l << 4)));
#pragma unroll
      for (int mi = 0; mi < 8; ++mi) a2[mi] = mfma16(pa[mi], vb, a2[mi]);
    }
    const int h = hc * 128 + wid * 16 + l;
#pragma unroll
    for (int mi = 0; mi < 8; ++mi)
#pragma unroll
      for (int jj = 0; jj < 4; ++jj) {
        const int q = mi * 16 + g * 4 + jj;
        float o = a2[mi][jj];
        o = (o >= 0.f) ? o : 0.01f * o;
        const size_t gi = (size_t)(gr0 + qrow0 + q) * 1024 + h;
        out[gi] = o + x[gi];
      }
  }
}

// ---------------- row LayerNorm in-place on d_out
__global__ __launch_bounds__(256) void ln_kernel(
    float* __restrict__ out, const float* __restrict__ gamma, const float* __restrict__ beta)
{
  const int row = blockIdx.x;
  float* p = out + (size_t)row * 1024;
  const int tidx = threadIdx.x;
  float4 v = *((const float4*)p + tidx);
  float s = v.x + v.y + v.z + v.w;
  float s2 = v.x * v.x + v.y * v.y + v.z * v.z + v.w * v.w;
#pragma unroll
  for (int st = 0; st < 6; ++st) {
    const int mk = 1 << st;
    s += __shfl_xor(s, mk, 64);
    s2 += __shfl_xor(s2, mk, 64);
  }
  __shared__ float red[8];
  const int wid = tidx >> 6, lane = tidx & 63;
  if (lane == 0) { red[wid] = s; red[4 + wid] = s2; }
  __syncthreads();
  s = red[0] + red[1] + red[2] + red[3];
  s2 = red[4] + red[5] + red[6] + red[7];
  const float mu = s * (1.0f / 1024.0f);
  float var = s2 * (1.0f / 1024.0f) - mu * mu;
  var = var < 0.f ? 0.f : var;
  const float rstd = 1.0f / sqrtf(var + 1e-5f);
  float4 gm = *((const float4*)gamma + tidx);
  float4 bt = *((const float4*)beta + tidx);
  v.x = (v.x - mu) * rstd * gm.x + bt.x;
  v.y = (v.y - mu) * rstd * gm.y + bt.y;
  v.z = (v.z - mu) * rstd * gm.z + bt.z;
  v.w = (v.w - mu) * rstd * gm.w + bt.w;
  *((float4*)p + tidx) = v;
}

extern "C" void kernel_launch(void* const* d_in, const int* in_sizes, int n_in,
                              void* d_out, int out_size, void* d_ws, size_t ws_size,
                              hipStream_t stream)
{
  (void)in_sizes; (void)n_in; (void)out_size;
  const float* x = (const float*)d_in[0];
  const float* Wq = (const float*)d_in[1];
  const float* bq = (const float*)d_in[2];
  const float* Wk = (const float*)d_in[3];
  const float* bk = (const float*)d_in[4];
  const float* Wv = (const float*)d_in[5];
  const float* bv = (const float*)d_in[6];
  const float* gamma = (const float*)d_in[7];
  const float* beta = (const float*)d_in[8];
  float* out = (float*)d_out;

  char* ws = (char*)d_ws;
  size_t off = 0;
  auto alloc = [&](size_t n) {
    char* p = ws + off;
    off = (off + n + 255) & ~(size_t)255;
    return p;
  };
  unsigned short* Wqkh = (unsigned short*)alloc(2048ull * 1024 * 2);
  unsigned short* Wqkl = (unsigned short*)alloc(2048ull * 1024 * 2);
  unsigned short* Wvh = (unsigned short*)alloc(1024ull * 1024 * 2);
  float* bqk = (float*)alloc(2048 * 4);
  const size_t fixed = off;
  const size_t perBatch = 58720256ull;  // xh+xl+QKh+QKl+VT for 4096 rows
  int NB = 8;
  while (NB > 1 && fixed + (size_t)NB * perBatch + 8192 > ws_size) NB >>= 1;
  const int M = NB * 4096;
  unsigned short* xh = (unsigned short*)alloc((size_t)M * 1024 * 2);
  unsigned short* xl = (unsigned short*)alloc((size_t)M * 1024 * 2);
  unsigned short* QKh = (unsigned short*)alloc((size_t)M * 2048 * 2);
  unsigned short* QKl = (unsigned short*)alloc((size_t)M * 2048 * 2);
  unsigned short* VT = (unsigned short*)alloc((size_t)M * 1024 * 2);

  hipLaunchKernelGGL(conv_w_kernel, dim3(1536), dim3(256), 0, stream,
                     Wq, Wk, Wv, bq, bk, Wqkh, Wqkl, Wvh, bqk);
  for (int c = 0; c < 8 / NB; ++c) {
    const int r0 = c * M;
    hipLaunchKernelGGL(conv_x_kernel, dim3(M / 2), dim3(256), 0, stream,
                       x + (size_t)r0 * 1024, xh, xl);
    // QK projection: A = xh/xl (M x 1024), B = Wqk (2048 x 1024), C = QK (M x 2048)
    hipLaunchKernelGGL((gemm256_kernel<true, false, false, 3>), dim3((M / 256) * 8), dim3(512), 0,
                       stream, xh, xl, Wqkh, Wqkl, bqk, QKh, QKl, 1024, 1024, 2048);
    // V^T: A = Wvh (1024 x 1024), B = xh (M x 1024), C = VT (1024 x M)
    hipLaunchKernelGGL((gemm256_kernel<false, true, true, 2>), dim3(4 * (M / 256)), dim3(512), 0,
                       stream, Wvh, (const unsigned short*)nullptr, xh,
                       (const unsigned short*)nullptr, bv, VT, (unsigned short*)nullptr,
                       1024, 1024, M);
    hipLaunchKernelGGL(attn_kernel, dim3(M / 128), dim3(512), 0, stream,
                       QKh, QKl, VT, x, out, M, r0);
  }
  hipLaunchKernelGGL(ln_kernel, dim3(32768), dim3(256), 0, stream, out, gamma, beta);
}

// Round 7
// 710.510 us; speedup vs baseline: 1.4917x; 1.0016x over previous
//
#include <hip/hip_runtime.h>

typedef __attribute__((ext_vector_type(8))) short short8;
typedef __attribute__((ext_vector_type(4))) float f32x4;

__device__ __forceinline__ unsigned short f2bf(float f) {
  unsigned int u = __float_as_uint(f);
  u = u + 0x7FFFu + ((u >> 16) & 1u);
  return (unsigned short)(u >> 16);
}
__device__ __forceinline__ float bf2f(unsigned short b) {
  return __uint_as_float(((unsigned int)b) << 16);
}
__device__ __forceinline__ f32x4 mfma16(short8 a, short8 b, f32x4 c) {
  return __builtin_amdgcn_mfma_f32_16x16x32_bf16(a, b, c, 0, 0, 0);
}
__device__ __forceinline__ void gload_lds16(const void* g, void* l) {
  __builtin_amdgcn_global_load_lds((const __attribute__((address_space(1))) void*)g,
                                   (__attribute__((address_space(3))) void*)l, 16, 0, 0);
}
#define BAR() __builtin_amdgcn_s_barrier()
#define VM0() asm volatile("s_waitcnt vmcnt(0)" ::: "memory")

// 16-lane (DPP-row) max+argmin-col reduce stage. All VALU-latency, no LDS.
template <int CTRL>
__device__ __forceinline__ void dpp_step(float& cv, int& cc) {
  float ov = __int_as_float(
      __builtin_amdgcn_update_dpp(0, __float_as_int(cv), CTRL, 0xF, 0xF, false));
  int oc = __builtin_amdgcn_update_dpp(0, cc, CTRL, 0xF, 0xF, false);
  if (ov > cv || (ov == cv && oc < cc)) { cv = ov; cc = oc; }
}

// ---------------- weight conversion: Wq,Wk -> hi/lo split; Wv -> hi; bias concat
__global__ __launch_bounds__(256) void conv_w_kernel(
    const float* __restrict__ Wq, const float* __restrict__ Wk, const float* __restrict__ Wv,
    const float* __restrict__ bq, const float* __restrict__ bk,
    unsigned short* __restrict__ Wqkh, unsigned short* __restrict__ Wqkl,
    unsigned short* __restrict__ Wvh, float* __restrict__ bqk)
{
  long long tid = (long long)blockIdx.x * 256 + threadIdx.x;
  long long base = tid * 8;
  if (base < 2097152) {
    const float* src = (base < 1048576) ? (Wq + base) : (Wk + (base - 1048576));
#pragma unroll
    for (int i = 0; i < 8; ++i) {
      float f = src[i];
      unsigned short h = f2bf(f);
      Wqkh[base + i] = h;
      Wqkl[base + i] = f2bf(f - bf2f(h));
    }
  } else if (base < 3145728) {
    long long b2 = base - 2097152;
#pragma unroll
    for (int i = 0; i < 8; ++i) Wvh[b2 + i] = f2bf(Wv[b2 + i]);
  }
  if (tid < 256) {
#pragma unroll
    for (int i = 0; i < 8; ++i) {
      int j = (int)tid * 8 + i;
      bqk[j] = (j < 1024) ? bq[j] : bk[j - 1024];
    }
  }
}

// ---------------- x -> hi/lo bf16 split
__global__ __launch_bounds__(256) void conv_x_kernel(
    const float* __restrict__ xs, unsigned short* __restrict__ xh, unsigned short* __restrict__ xl)
{
  long long base = ((long long)blockIdx.x * 256 + threadIdx.x) * 8;
  float4 a = *(const float4*)(xs + base);
  float4 b = *(const float4*)(xs + base + 4);
  float v[8] = {a.x, a.y, a.z, a.w, b.x, b.y, b.z, b.w};
  short8 hv, lv;
#pragma unroll
  for (int i = 0; i < 8; ++i) {
    unsigned short h = f2bf(v[i]);
    hv[i] = (short)h;
    lv[i] = (short)f2bf(v[i] - bf2f(h));
  }
  *(short8*)(xh + base) = hv;
  *(short8*)(xl + base) = lv;
}

// ---------------- 256x256-tile B^T GEMM, BK=32, 8 waves, dbuf LDS (unchanged from R6).
template <bool SPLIT, bool BIASROW, bool FASTA, int LGF>
__global__ __launch_bounds__(512, 2) void gemm256_kernel(
    const unsigned short* __restrict__ Aph, const unsigned short* __restrict__ Apl,
    const unsigned short* __restrict__ Bph, const unsigned short* __restrict__ Bpl,
    const float* __restrict__ bias,
    unsigned short* __restrict__ Ch, unsigned short* __restrict__ Cl,
    int lda, int ldb, int ldc)
{
  constexpr int TILES = SPLIT ? 4 : 2;
  constexpr int BUFS = TILES * 16384;
  constexpr int NP = TILES * 2;  // 16B-granule staging passes per K-tile
  __shared__ char lds[2 * BUFS];
  const int tid = threadIdx.x;
  const int wid = tid >> 6, lane = tid & 63;
  const int l = lane & 15, g = lane >> 4;
  const int wm = wid >> 2, wn = wid & 3;

  // bijective XCD-chunk swizzle (nwg % 8 == 0)
  const int nwg = gridDim.x;
  const int cpx = nwg >> 3;
  const int bid = (int)blockIdx.x;
  const int lin = (bid & 7) * cpx + (bid >> 3);
  const int tf = lin & ((1 << LGF) - 1), ts = lin >> LGF;
  const int ablk = FASTA ? tf : ts, bblk = FASTA ? ts : tf;
  const int arow0 = ablk * 256, brow0 = bblk * 256;

  // staging: pass p covers tile tp=p>>1, half h=p&1 (512 granules of 16B)
  const char* gsrc[NP];
  int ldsoff[NP];
#pragma unroll
  for (int p = 0; p < NP; ++p) {
    const int tp = p >> 1, h = p & 1;
    const int pi = h * 512 + wid * 64 + lane;
    const int row = pi >> 2;
    const int gl = (pi & 3) ^ ((row >> 1) & 3);
    const unsigned short* base =
        SPLIT ? ((tp == 0) ? Aph : (tp == 1) ? Apl : (tp == 2) ? Bph : Bpl)
              : ((tp == 0) ? Aph : Bph);
    const int r0 = (tp >= TILES / 2) ? brow0 : arow0;
    const int ld = (tp >= TILES / 2) ? ldb : lda;
    gsrc[p] = (const char*)(base + (size_t)(r0 + row) * ld + gl * 8);
    ldsoff[p] = tp * 16384 + h * 8192 + wid * 1024;
  }

  f32x4 acc[8][4];
#pragma unroll
  for (int i = 0; i < 8; ++i)
#pragma unroll
    for (int j = 0; j < 4; ++j) acc[i][j] = (f32x4){0.f, 0.f, 0.f, 0.f};

  // prologue: stage K-tile 0 into buf 0
#pragma unroll
  for (int p = 0; p < NP; ++p) gload_lds16(gsrc[p], &lds[ldsoff[p]]);
  VM0();
  BAR();

  const int nt = 32;  // K = 1024, BK = 32
#pragma unroll 1
  for (int t = 0; t < nt; ++t) {
    const int cur = (t & 1) ? BUFS : 0;
    const int nxt = BUFS - cur;
    const char* lc = lds + cur;
    const long long kadv = (long long)(t + 1) * 64;  // bytes per K-tile step

    // issue next tile's staging first (in-flight across the whole tile body)
    if (t < nt - 1) {
#pragma unroll
      for (int p = 0; p < NP; ++p) gload_lds16(gsrc[p] + kadv, &lds[nxt + ldsoff[p]]);
    }

    // flat compute on cur; compiler schedules ds_reads/MFMA interleave freely.
    short8 bh[4], bl_[4];
#pragma unroll
    for (int ni = 0; ni < 4; ++ni) {
      const int row = wn * 64 + ni * 16 + l;
      const int off = row * 64 + ((g ^ ((row >> 1) & 3)) << 4);
      bh[ni] = *(const short8*)(lc + (SPLIT ? 32768 : 16384) + off);
      if (SPLIT) bl_[ni] = *(const short8*)(lc + 49152 + off);
    }
#pragma unroll
    for (int mi = 0; mi < 8; ++mi) {
      const int row = wm * 128 + mi * 16 + l;
      const int off = row * 64 + ((g ^ ((row >> 1) & 3)) << 4);
      short8 ah = *(const short8*)(lc + off);
      short8 al_ = ah;
      if (SPLIT) al_ = *(const short8*)(lc + 16384 + off);
#pragma unroll
      for (int ni = 0; ni < 4; ++ni) {
        acc[mi][ni] = mfma16(ah, bh[ni], acc[mi][ni]);
        if (SPLIT) {
          acc[mi][ni] = mfma16(ah, bl_[ni], acc[mi][ni]);
          acc[mi][ni] = mfma16(al_, bh[ni], acc[mi][ni]);
        }
      }
    }

    VM0();  // own staging loads done; barrier makes all waves' staging visible
    BAR();
  }

#pragma unroll
  for (int mi = 0; mi < 8; ++mi)
#pragma unroll
    for (int ni = 0; ni < 4; ++ni) {
      const int gcol = brow0 + wn * 64 + ni * 16 + l;
      const int grow0v = arow0 + wm * 128 + mi * 16 + g * 4;
#pragma unroll
      for (int j = 0; j < 4; ++j) {
        const int grow = grow0v + j;
        float val = acc[mi][ni][j] + (BIASROW ? bias[grow] : bias[gcol]);
        unsigned short hh = f2bf(val);
        Ch[(size_t)grow * ldc + gcol] = hh;
        if (SPLIT) Cl[(size_t)grow * ldc + gcol] = f2bf(val - bf2f(hh));
      }
    }
}

// ---------------- per-window attention, 64 q-rows per block (2 blocks/window),
// 256 threads / 4 waves, LDS 48 KiB -> 2-3 blocks/CU co-residency.
// QK^T: dbuf 24KB staging, one __syncthreads per K-tile, stage issued after the
// barrier (in flight across compute). Exact top-32 (DPP) -> softmax ->
// PV with dbuf 16KB V chunks (128h x 64m), same issue-after-barrier pattern.
// P (bf16 64x128, swizzled) at lds[0,16K).
__global__ __launch_bounds__(256, 3) void attn_kernel(
    const unsigned short* __restrict__ QKh, const unsigned short* __restrict__ QKl,
    const unsigned short* __restrict__ VT, const float* __restrict__ x,
    float* __restrict__ out, int Mc, int gr0)
{
  __shared__ char lds[49152];  // 2 QK bufs @0/24576; later P @0..16K, V bufs @16384/32768
  const int tid = threadIdx.x;
  const int wid = tid >> 6, lane = tid & 63;
  const int l = lane & 15, g = lane >> 4;
  // XCD swizzle: sibling half-windows adjacent -> same XCD (K tile L2-shared)
  const int nblk = (int)gridDim.x;  // multiple of 8
  const int bid = (int)blockIdx.x;
  const int lin = (bid & 7) * (nblk >> 3) + (bid >> 3);
  const int winid = lin >> 1, qhalf = lin & 1;
  const int qrow0 = winid * 128 + qhalf * 64;
  const int krow0 = winid * 128;

  // ---- QK staging setup: buf = 24KB {Qh@0(4K), Ql@4K, Kh@8K(8K), Kl@16K(8K)}
  // 6 passes x 256 granules of 16B; source column pre-permuted (XOR involution).
  const char* gsrc[6];
  int ldsoff[6];
  {
    const int rq = tid >> 2;
    const int slq = (tid & 3) ^ ((rq >> 1) & 3);
    gsrc[0] = (const char*)(QKh + (size_t)(qrow0 + rq) * 2048 + slq * 8);
    gsrc[1] = (const char*)(QKl + (size_t)(qrow0 + rq) * 2048 + slq * 8);
    ldsoff[0] = tid * 16;
    ldsoff[1] = 4096 + tid * 16;
#pragma unroll
    for (int kp = 0; kp < 2; ++kp) {
      const int r = kp * 64 + (tid >> 2);
      const int sl = (tid & 3) ^ ((r >> 1) & 3);
      gsrc[2 + kp] = (const char*)(QKh + (size_t)(krow0 + r) * 2048 + 1024 + sl * 8);
      gsrc[4 + kp] = (const char*)(QKl + (size_t)(krow0 + r) * 2048 + 1024 + sl * 8);
      ldsoff[2 + kp] = 8192 + (kp * 256 + tid) * 16;
      ldsoff[4 + kp] = 16384 + (kp * 256 + tid) * 16;
    }
  }

  f32x4 acc[8];
#pragma unroll
  for (int ni = 0; ni < 8; ++ni) acc[ni] = (f32x4){0.f, 0.f, 0.f, 0.f};

  // prologue: issue tile 0 into buf 0
#pragma unroll
  for (int p = 0; p < 6; ++p) gload_lds16(gsrc[p], lds + ldsoff[p]);

  const int qrow = wid * 16 + l;
  const int qoff = qrow * 64 + ((g ^ ((qrow >> 1) & 3)) << 4);

#pragma unroll 1
  for (int t = 0; t < 32; ++t) {
    __syncthreads();  // vmcnt(0) drain (tile t's loads, issued one tile ago) + barrier
    if (t < 31) {
      const long long adv = (long long)(t + 1) * 64;
      const int nb = ((t + 1) & 1) * 24576;
#pragma unroll
      for (int p = 0; p < 6; ++p) gload_lds16(gsrc[p] + adv, lds + nb + ldsoff[p]);
    }
    const char* cb = lds + (t & 1) * 24576;
    const short8 qhv = *(const short8*)(cb + qoff);
    const short8 qlv = *(const short8*)(cb + 4096 + qoff);
#pragma unroll
    for (int ni = 0; ni < 8; ++ni) {
      const int krow = ni * 16 + l;
      const int koff = krow * 64 + ((g ^ ((krow >> 1) & 3)) << 4);
      const short8 khv = *(const short8*)(cb + 8192 + koff);
      const short8 klv = *(const short8*)(cb + 16384 + koff);
      acc[ni] = mfma16(qhv, khv, acc[ni]);
      acc[ni] = mfma16(qhv, klv, acc[ni]);
      acc[ni] = mfma16(qlv, khv, acc[ni]);
    }
  }
  __syncthreads();  // all waves done with last QK tile -> bufs reusable

  // ---- V staging setup: chunk c (hc=c>>1 of 8 h-blocks, mc=c&1 of 2 key-halves)
  // = V^T[hc*128..+128][krow0 + mc*64 ..+64], 16KB, dbuf @16384/32768.
  const char* vsrc[4];
  int vdst[4];
#pragma unroll
  for (int p = 0; p < 4; ++p) {
    const int gix = p * 256 + tid;
    const int vh = gix >> 3, vsl = gix & 7;
    const int vmg = vsl ^ (vh & 7);
    vsrc[p] = (const char*)(VT + (size_t)vh * Mc + krow0 + vmg * 8);
    vdst[p] = gix * 16;
  }
  const long long hstep = (long long)Mc * 256;  // bytes per hc step (128 VT rows)

  // pre-issue V chunk 0 (hidden under top-k)
#pragma unroll
  for (int p = 0; p < 4; ++p) gload_lds16(vsrc[p], lds + 16384 + vdst[p]);

  // ---- exact top-32 + softmax. Thread owns rows wid*16 + g*4 + j (j=0..3);
  // row's 128 scores live across its 16-lane group: col = ni*16 + l.
  const float s_scale = 1.0f / 32.0f;
  float vc[4][8];
  float rmax[4], ssum[4];
  unsigned int sel[4];
#pragma unroll
  for (int j = 0; j < 4; ++j) {
#pragma unroll
    for (int ni = 0; ni < 8; ++ni) vc[j][ni] = acc[ni][j] * s_scale;
    ssum[j] = 0.f;
    sel[j] = 0u;
    rmax[j] = 0.f;
  }
#pragma unroll 1
  for (int t = 0; t < 32; ++t) {
#pragma unroll
    for (int j = 0; j < 4; ++j) {
      float bv = vc[j][0];
      int bi = 0;
#pragma unroll
      for (int i = 1; i < 8; ++i)
        if (vc[j][i] > bv) { bv = vc[j][i]; bi = i; }
      float cv = bv;
      int cc = (bi << 4) | l;  // col = (bi<<4)|l; ties -> min col (matches lax.top_k)
      dpp_step<0xB1>(cv, cc);   // quad_perm(1,0,3,2): xor 1
      dpp_step<0x4E>(cv, cc);   // quad_perm(2,3,0,1): xor 2
      dpp_step<0x141>(cv, cc);  // row_half_mirror
      dpp_step<0x140>(cv, cc);  // row_mirror
      if (t == 0) rmax[j] = cv;
      ssum[j] += __expf(cv - rmax[j]);
      const bool hit = ((cc & 15) == l);
      const int ci = cc >> 4;
#pragma unroll
      for (int i = 0; i < 8; ++i)
        if (hit && ci == i) vc[j][i] = -__builtin_inff();
      sel[j] |= (hit ? (1u << ci) : 0u);
    }
  }
  // P store (bf16, swizzled) into lds[0..16K) — overwrites QK buf0 (done)
#pragma unroll
  for (int j = 0; j < 4; ++j) {
    const int qr = wid * 16 + g * 4 + j;
    const float isum = 1.0f / ssum[j];
#pragma unroll
    for (int ni = 0; ni < 8; ++ni) {
      const float p =
          ((sel[j] >> ni) & 1u) ? (__expf(acc[ni][j] * s_scale - rmax[j]) * isum) : 0.0f;
      const int col = ni * 16 + l;
      const int addr = qr * 256 + ((col * 2) ^ ((qr & 7) << 4));
      *(unsigned short*)(lds + addr) = f2bf(p);
    }
  }

  // ---- phase 2: out = P @ V over 16 chunks (8 hc x 2 mc); wave owns 32 h per chunk.
  f32x4 a2[4][2];
#pragma unroll 1
  for (int c = 0; c < 16; ++c) {
    __syncthreads();  // drains chunk c's stage (issued one chunk ago) + flushes P (c==0)
    if (c < 15) {
      const int c1 = c + 1;
      const long long soff = (long long)(c1 >> 1) * hstep + (c1 & 1) * 128;
      const int nb = 16384 + (c1 & 1) * 16384;
#pragma unroll
      for (int p = 0; p < 4; ++p) gload_lds16(vsrc[p] + soff, lds + nb + vdst[p]);
    }
    const int mc = c & 1;
    const char* vbb = lds + 16384 + mc * 16384;
    if (mc == 0) {
#pragma unroll
      for (int i = 0; i < 4; ++i)
#pragma unroll
        for (int j = 0; j < 2; ++j) a2[i][j] = (f32x4){0.f, 0.f, 0.f, 0.f};
    }
#pragma unroll
    for (int ks = 0; ks < 2; ++ks) {
      short8 pa[4];
#pragma unroll
      for (int mi = 0; mi < 4; ++mi) {
        const int q = mi * 16 + l;
        pa[mi] = *(const short8*)(lds + q * 256 +
                                  ((mc * 128 + ks * 64 + g * 16) ^ ((q & 7) << 4)));
      }
#pragma unroll
      for (int ni = 0; ni < 2; ++ni) {
        const int hl = wid * 32 + ni * 16 + l;
        const short8 vb =
            *(const short8*)(vbb + hl * 128 + ((ks * 64 + g * 16) ^ ((hl & 7) << 4)));
#pragma unroll
        for (int mi = 0; mi < 4; ++mi) a2[mi][ni] = mfma16(pa[mi], vb, a2[mi][ni]);
      }
    }
    if (mc == 1) {
      const int hc = c >> 1;
#pragma unroll
      for (int mi = 0; mi < 4; ++mi)
#pragma unroll
        for (int ni = 0; ni < 2; ++ni) {
          const int h = hc * 128 + wid * 32 + ni * 16 + l;
#pragma unroll
          for (int jj = 0; jj < 4; ++jj) {
            const int q = mi * 16 + g * 4 + jj;
            float o = a2[mi][ni][jj];
            o = (o >= 0.f) ? o : 0.01f * o;
            const size_t gi = (size_t)(gr0 + qrow0 + q) * 1024 + h;
            out[gi] = o + x[gi];
          }
        }
    }
  }
}

// ---------------- row LayerNorm in-place on d_out
__global__ __launch_bounds__(256) void ln_kernel(
    float* __restrict__ out, const float* __restrict__ gamma, const float* __restrict__ beta)
{
  const int row = blockIdx.x;
  float* p = out + (size_t)row * 1024;
  const int tidx = threadIdx.x;
  float4 v = *((const float4*)p + tidx);
  float s = v.x + v.y + v.z + v.w;
  float s2 = v.x * v.x + v.y * v.y + v.z * v.z + v.w * v.w;
#pragma unroll
  for (int st = 0; st < 6; ++st) {
    const int mk = 1 << st;
    s += __shfl_xor(s, mk, 64);
    s2 += __shfl_xor(s2, mk, 64);
  }
  __shared__ float red[8];
  const int wid = tidx >> 6, lane = tidx & 63;
  if (lane == 0) { red[wid] = s; red[4 + wid] = s2; }
  __syncthreads();
  s = red[0] + red[1] + red[2] + red[3];
  s2 = red[4] + red[5] + red[6] + red[7];
  const float mu = s * (1.0f / 1024.0f);
  float var = s2 * (1.0f / 1024.0f) - mu * mu;
  var = var < 0.f ? 0.f : var;
  const float rstd = 1.0f / sqrtf(var + 1e-5f);
  float4 gm = *((const float4*)gamma + tidx);
  float4 bt = *((const float4*)beta + tidx);
  v.x = (v.x - mu) * rstd * gm.x + bt.x;
  v.y = (v.y - mu) * rstd * gm.y + bt.y;
  v.z = (v.z - mu) * rstd * gm.z + bt.z;
  v.w = (v.w - mu) * rstd * gm.w + bt.w;
  *((float4*)p + tidx) = v;
}

extern "C" void kernel_launch(void* const* d_in, const int* in_sizes, int n_in,
                              void* d_out, int out_size, void* d_ws, size_t ws_size,
                              hipStream_t stream)
{
  (void)in_sizes; (void)n_in; (void)out_size;
  const float* x = (const float*)d_in[0];
  const float* Wq = (const float*)d_in[1];
  const float* bq = (const float*)d_in[2];
  const float* Wk = (const float*)d_in[3];
  const float* bk = (const float*)d_in[4];
  const float* Wv = (const float*)d_in[5];
  const float* bv = (const float*)d_in[6];
  const float* gamma = (const float*)d_in[7];
  const float* beta = (const float*)d_in[8];
  float* out = (float*)d_out;

  char* ws = (char*)d_ws;
  size_t off = 0;
  auto alloc = [&](size_t n) {
    char* p = ws + off;
    off = (off + n + 255) & ~(size_t)255;
    return p;
  };
  unsigned short* Wqkh = (unsigned short*)alloc(2048ull * 1024 * 2);
  unsigned short* Wqkl = (unsigned short*)alloc(2048ull * 1024 * 2);
  unsigned short* Wvh = (unsigned short*)alloc(1024ull * 1024 * 2);
  float* bqk = (float*)alloc(2048 * 4);
  const size_t fixed = off;
  const size_t perBatch = 58720256ull;  // xh+xl+QKh+QKl+VT for 4096 rows
  int NB = 8;
  while (NB > 1 && fixed + (size_t)NB * perBatch + 8192 > ws_size) NB >>= 1;
  const int M = NB * 4096;
  unsigned short* xh = (unsigned short*)alloc((size_t)M * 1024 * 2);
  unsigned short* xl = (unsigned short*)alloc((size_t)M * 1024 * 2);
  unsigned short* QKh = (unsigned short*)alloc((size_t)M * 2048 * 2);
  unsigned short* QKl = (unsigned short*)alloc((size_t)M * 2048 * 2);
  unsigned short* VT = (unsigned short*)alloc((size_t)M * 1024 * 2);

  hipLaunchKernelGGL(conv_w_kernel, dim3(1536), dim3(256), 0, stream,
                     Wq, Wk, Wv, bq, bk, Wqkh, Wqkl, Wvh, bqk);
  for (int c = 0; c < 8 / NB; ++c) {
    const int r0 = c * M;
    hipLaunchKernelGGL(conv_x_kernel, dim3(M / 2), dim3(256), 0, stream,
                       x + (size_t)r0 * 1024, xh, xl);
    // QK projection: A = xh/xl (M x 1024), B = Wqk (2048 x 1024), C = QK (M x 2048)
    hipLaunchKernelGGL((gemm256_kernel<true, false, false, 3>), dim3((M / 256) * 8), dim3(512), 0,
                       stream, xh, xl, Wqkh, Wqkl, bqk, QKh, QKl, 1024, 1024, 2048);
    // V^T: A = Wvh (1024 x 1024), B = xh (M x 1024), C = VT (1024 x M)
    hipLaunchKernelGGL((gemm256_kernel<false, true, true, 2>), dim3(4 * (M / 256)), dim3(512), 0,
                       stream, Wvh, (const unsigned short*)nullptr, xh,
                       (const unsigned short*)nullptr, bv, VT, (unsigned short*)nullptr,
                       1024, 1024, M);
    hipLaunchKernelGGL(attn_kernel, dim3(M / 64), dim3(256), 0, stream,
                       QKh, QKl, VT, x, out, M, r0);
  }
  hipLaunchKernelGGL(ln_kernel, dim3(32768), dim3(256), 0, stream, out, gamma, beta);
}

// Round 9
// 616.305 us; speedup vs baseline: 1.7197x; 1.1529x over previous
//
#include <hip/hip_runtime.h>

typedef __attribute__((ext_vector_type(8))) short short8;
typedef __attribute__((ext_vector_type(4))) float f32x4;

__device__ __forceinline__ unsigned short f2bf(float f) {
  unsigned int u = __float_as_uint(f);
  u = u + 0x7FFFu + ((u >> 16) & 1u);
  return (unsigned short)(u >> 16);
}
__device__ __forceinline__ float bf2f(unsigned short b) {
  return __uint_as_float(((unsigned int)b) << 16);
}
__device__ __forceinline__ f32x4 mfma16(short8 a, short8 b, f32x4 c) {
  return __builtin_amdgcn_mfma_f32_16x16x32_bf16(a, b, c, 0, 0, 0);
}
__device__ __forceinline__ void gload_lds16(const void* g, void* l) {
  __builtin_amdgcn_global_load_lds((const __attribute__((address_space(1))) void*)g,
                                   (__attribute__((address_space(3))) void*)l, 16, 0, 0);
}
#define BAR() __builtin_amdgcn_s_barrier()
#define VM0() asm volatile("s_waitcnt vmcnt(0)" ::: "memory")

// 16-lane (DPP-row) max+argmin-col reduce stage. All VALU-latency, no LDS.
template <int CTRL>
__device__ __forceinline__ void dpp_step(float& cv, int& cc) {
  float ov = __int_as_float(
      __builtin_amdgcn_update_dpp(0, __float_as_int(cv), CTRL, 0xF, 0xF, false));
  int oc = __builtin_amdgcn_update_dpp(0, cc, CTRL, 0xF, 0xF, false);
  if (ov > cv || (ov == cv && oc < cc)) { cv = ov; cc = oc; }
}

// ---------------- Wv -> bf16
__global__ __launch_bounds__(256) void conv_wv_kernel(
    const float* __restrict__ Wv, unsigned short* __restrict__ Wvh)
{
  long long base = ((long long)blockIdx.x * 256 + threadIdx.x) * 8;
#pragma unroll
  for (int i = 0; i < 8; ++i) Wvh[base + i] = f2bf(Wv[base + i]);
}

// ---------------- wv = Wk^T bq (f32). (u_i and c are row-constant in S -> dropped:
// they shift all 128 scores of a row equally, which is invariant for top-k AND softmax.)
__global__ __launch_bounds__(256) void wv_kernel(
    const float* __restrict__ Wk, const float* __restrict__ bq, float* __restrict__ wv)
{
  const int h = blockIdx.x * 256 + threadIdx.x;
  float av = 0.f;
  for (int o = 0; o < 1024; ++o) av += Wk[(size_t)o * 1024 + h] * bq[o];
  wv[h] = av;
}

// ---------------- Gt[a][h] = sum_o Wk[o][a] * Wq[o][h]  (exact f32, 64x64 tiles)
__global__ __launch_bounds__(256) void gt_kernel(
    const float* __restrict__ Wq, const float* __restrict__ Wk, float* __restrict__ Gt)
{
  __shared__ float lA[64][68], lB[64][68];
  const int tid = threadIdx.x;
  const int a0 = blockIdx.x * 64, h0 = blockIdx.y * 64;
  const int ta = tid & 15, th = tid >> 4;
  float acc[4][4];
#pragma unroll
  for (int i = 0; i < 4; ++i)
#pragma unroll
    for (int j = 0; j < 4; ++j) acc[i][j] = 0.f;
  const int orow = tid >> 2, q = tid & 3;
  for (int o0 = 0; o0 < 1024; o0 += 64) {
    __syncthreads();
#pragma unroll
    for (int i = 0; i < 4; ++i) {
      *(float4*)&lA[orow][q * 16 + i * 4] =
          *(const float4*)&Wk[(size_t)(o0 + orow) * 1024 + a0 + q * 16 + i * 4];
      *(float4*)&lB[orow][q * 16 + i * 4] =
          *(const float4*)&Wq[(size_t)(o0 + orow) * 1024 + h0 + q * 16 + i * 4];
    }
    __syncthreads();
#pragma unroll 8
    for (int o = 0; o < 64; ++o) {
      float4 av = *(const float4*)&lA[o][ta * 4];
      float4 bv = *(const float4*)&lB[o][th * 4];
      float aa[4] = {av.x, av.y, av.z, av.w}, bb[4] = {bv.x, bv.y, bv.z, bv.w};
#pragma unroll
      for (int i = 0; i < 4; ++i)
#pragma unroll
        for (int j = 0; j < 4; ++j) acc[i][j] += aa[i] * bb[j];
    }
  }
#pragma unroll
  for (int i = 0; i < 4; ++i)
#pragma unroll
    for (int j = 0; j < 4; ++j)
      Gt[(size_t)(a0 + ta * 4 + i) * 1024 + h0 + th * 4 + j] = acc[i][j];
}

// ---------------- Gt f32 -> hi/lo bf16 split
__global__ __launch_bounds__(256) void gsplit_kernel(
    const float* __restrict__ Gt, unsigned short* __restrict__ Gth,
    unsigned short* __restrict__ Gtl)
{
  long long base = ((long long)blockIdx.x * 256 + threadIdx.x) * 8;
#pragma unroll
  for (int i = 0; i < 8; ++i) {
    float f = Gt[base + i];
    unsigned short h = f2bf(f);
    Gth[base + i] = h;
    Gtl[base + i] = f2bf(f - bf2f(h));
  }
}

// ---------------- x -> hi/lo bf16 split
__global__ __launch_bounds__(256) void conv_x_kernel(
    const float* __restrict__ xs, unsigned short* __restrict__ xh, unsigned short* __restrict__ xl)
{
  long long base = ((long long)blockIdx.x * 256 + threadIdx.x) * 8;
  float4 a = *(const float4*)(xs + base);
  float4 b = *(const float4*)(xs + base + 4);
  float v[8] = {a.x, a.y, a.z, a.w, b.x, b.y, b.z, b.w};
  short8 hv, lv;
#pragma unroll
  for (int i = 0; i < 8; ++i) {
    unsigned short h = f2bf(v[i]);
    hv[i] = (short)h;
    lv[i] = (short)f2bf(v[i] - bf2f(h));
  }
  *(short8*)(xh + base) = hv;
  *(short8*)(xl + base) = lv;
}

// ---------------- 256x256-tile B^T GEMM, BK=32, 8 waves, dbuf LDS.
// BIASMODE: 0 none, 1 row (bias[grow]), 2 col (bias[gcol], added in f32 BEFORE split).
template <bool SPLIT, int BIASMODE, bool FASTA, int LGF>
__global__ __launch_bounds__(512, 2) void gemm256_kernel(
    const unsigned short* __restrict__ Aph, const unsigned short* __restrict__ Apl,
    const unsigned short* __restrict__ Bph, const unsigned short* __restrict__ Bpl,
    const float* __restrict__ bias,
    unsigned short* __restrict__ Ch, unsigned short* __restrict__ Cl,
    int lda, int ldb, int ldc)
{
  constexpr int TILES = SPLIT ? 4 : 2;
  constexpr int BUFS = TILES * 16384;
  constexpr int NP = TILES * 2;  // 16B-granule staging passes per K-tile
  __shared__ char lds[2 * BUFS];
  const int tid = threadIdx.x;
  const int wid = tid >> 6, lane = tid & 63;
  const int l = lane & 15, g = lane >> 4;
  const int wm = wid >> 2, wn = wid & 3;

  // bijective XCD-chunk swizzle (nwg % 8 == 0)
  const int nwg = gridDim.x;
  const int cpx = nwg >> 3;
  const int bid = (int)blockIdx.x;
  const int lin = (bid & 7) * cpx + (bid >> 3);
  const int tf = lin & ((1 << LGF) - 1), ts = lin >> LGF;
  const int ablk = FASTA ? tf : ts, bblk = FASTA ? ts : tf;
  const int arow0 = ablk * 256, brow0 = bblk * 256;

  // staging: pass p covers tile tp=p>>1, half h=p&1 (512 granules of 16B)
  const char* gsrc[NP];
  int ldsoff[NP];
#pragma unroll
  for (int p = 0; p < NP; ++p) {
    const int tp = p >> 1, h = p & 1;
    const int pi = h * 512 + wid * 64 + lane;
    const int row = pi >> 2;
    const int gl = (pi & 3) ^ ((row >> 1) & 3);
    const unsigned short* base =
        SPLIT ? ((tp == 0) ? Aph : (tp == 1) ? Apl : (tp == 2) ? Bph : Bpl)
              : ((tp == 0) ? Aph : Bph);
    const int r0 = (tp >= TILES / 2) ? brow0 : arow0;
    const int ld = (tp >= TILES / 2) ? ldb : lda;
    gsrc[p] = (const char*)(base + (size_t)(r0 + row) * ld + gl * 8);
    ldsoff[p] = tp * 16384 + h * 8192 + wid * 1024;
  }

  f32x4 acc[8][4];
#pragma unroll
  for (int i = 0; i < 8; ++i)
#pragma unroll
    for (int j = 0; j < 4; ++j) acc[i][j] = (f32x4){0.f, 0.f, 0.f, 0.f};

  // prologue: stage K-tile 0 into buf 0
#pragma unroll
  for (int p = 0; p < NP; ++p) gload_lds16(gsrc[p], &lds[ldsoff[p]]);
  VM0();
  BAR();

  const int nt = 32;  // K = 1024, BK = 32
#pragma unroll 1
  for (int t = 0; t < nt; ++t) {
    const int cur = (t & 1) ? BUFS : 0;
    const int nxt = BUFS - cur;
    const char* lc = lds + cur;
    const long long kadv = (long long)(t + 1) * 64;  // bytes per K-tile step

    // issue next tile's staging first (in-flight across the whole tile body)
    if (t < nt - 1) {
#pragma unroll
      for (int p = 0; p < NP; ++p) gload_lds16(gsrc[p] + kadv, &lds[nxt + ldsoff[p]]);
    }

    // flat compute on cur; compiler schedules ds_reads/MFMA interleave freely.
    short8 bh[4], bl_[4];
#pragma unroll
    for (int ni = 0; ni < 4; ++ni) {
      const int row = wn * 64 + ni * 16 + l;
      const int off = row * 64 + ((g ^ ((row >> 1) & 3)) << 4);
      bh[ni] = *(const short8*)(lc + (SPLIT ? 32768 : 16384) + off);
      if (SPLIT) bl_[ni] = *(const short8*)(lc + 49152 + off);
    }
#pragma unroll
    for (int mi = 0; mi < 8; ++mi) {
      const int row = wm * 128 + mi * 16 + l;
      const int off = row * 64 + ((g ^ ((row >> 1) & 3)) << 4);
      short8 ah = *(const short8*)(lc + off);
      short8 al_ = ah;
      if (SPLIT) al_ = *(const short8*)(lc + 16384 + off);
#pragma unroll
      for (int ni = 0; ni < 4; ++ni) {
        acc[mi][ni] = mfma16(ah, bh[ni], acc[mi][ni]);
        if (SPLIT) {
          acc[mi][ni] = mfma16(ah, bl_[ni], acc[mi][ni]);
          acc[mi][ni] = mfma16(al_, bh[ni], acc[mi][ni]);
        }
      }
    }

    VM0();  // own staging loads done; barrier makes all waves' staging visible
    BAR();
  }

#pragma unroll
  for (int mi = 0; mi < 8; ++mi)
#pragma unroll
    for (int ni = 0; ni < 4; ++ni) {
      const int gcol = brow0 + wn * 64 + ni * 16 + l;
      const int grow0v = arow0 + wm * 128 + mi * 16 + g * 4;
#pragma unroll
      for (int j = 0; j < 4; ++j) {
        const int grow = grow0v + j;
        float bv = 0.f;
        if (BIASMODE == 1) bv = bias[grow];
        if (BIASMODE == 2) bv = bias[gcol];
        float val = acc[mi][ni][j] + bv;
        unsigned short hh = f2bf(val);
        Ch[(size_t)grow * ldc + gcol] = hh;
        if (SPLIT) Cl[(size_t)grow * ldc + gcol] = f2bf(val - bf2f(hh));
      }
    }
}

// ---------------- per-window attention, 64 q-rows per block (2 blocks/window).
// Ranking/softmax score: S'_ij = Y'_i . x_j (Y' = x.G^T + wv has v_j folded in;
// the remaining u_i + c terms are row-constant -> exactly invariant for top-k
// and softmax). Structure IDENTICAL to the proven R7 kernel.
__global__ __launch_bounds__(256, 3) void attn_kernel(
    const unsigned short* __restrict__ Yh, const unsigned short* __restrict__ Yl,
    const unsigned short* __restrict__ xbh, const unsigned short* __restrict__ xbl,
    const unsigned short* __restrict__ VT, const float* __restrict__ x,
    float* __restrict__ out, int Mc, int gr0)
{
  __shared__ char lds[49152];  // 2 QK bufs @0/24576; later P @0..16K, V bufs @16384/32768
  const int tid = threadIdx.x;
  const int wid = tid >> 6, lane = tid & 63;
  const int l = lane & 15, g = lane >> 4;
  const int nblk = (int)gridDim.x;  // multiple of 8
  const int bid = (int)blockIdx.x;
  const int lin = (bid & 7) * (nblk >> 3) + (bid >> 3);
  const int winid = lin >> 1, qhalf = lin & 1;
  const int qrow0 = winid * 128 + qhalf * 64;
  const int krow0 = winid * 128;

  // ---- QK staging: buf = 24KB {Yh@0(4K), Yl@4K, Kh@8K(8K), Kl@16K(8K)}
  const char* gsrc[6];
  int ldsoff[6];
  {
    const int rq = tid >> 2;
    const int slq = (tid & 3) ^ ((rq >> 1) & 3);
    gsrc[0] = (const char*)(Yh + (size_t)(qrow0 + rq) * 1024 + slq * 8);
    gsrc[1] = (const char*)(Yl + (size_t)(qrow0 + rq) * 1024 + slq * 8);
    ldsoff[0] = tid * 16;
    ldsoff[1] = 4096 + tid * 16;
#pragma unroll
    for (int kp = 0; kp < 2; ++kp) {
      const int r = kp * 64 + (tid >> 2);
      const int sl = (tid & 3) ^ ((r >> 1) & 3);
      gsrc[2 + kp] = (const char*)(xbh + (size_t)(krow0 + r) * 1024 + sl * 8);
      gsrc[4 + kp] = (const char*)(xbl + (size_t)(krow0 + r) * 1024 + sl * 8);
      ldsoff[2 + kp] = 8192 + (kp * 256 + tid) * 16;
      ldsoff[4 + kp] = 16384 + (kp * 256 + tid) * 16;
    }
  }

  f32x4 acc[8];
#pragma unroll
  for (int ni = 0; ni < 8; ++ni) acc[ni] = (f32x4){0.f, 0.f, 0.f, 0.f};

  // prologue: issue tile 0 into buf 0
#pragma unroll
  for (int p = 0; p < 6; ++p) gload_lds16(gsrc[p], lds + ldsoff[p]);

  const int qrow = wid * 16 + l;
  const int qoff = qrow * 64 + ((g ^ ((qrow >> 1) & 3)) << 4);

#pragma unroll 1
  for (int t = 0; t < 32; ++t) {
    __syncthreads();  // vmcnt(0) drain (tile t's loads, issued one tile ago) + barrier
    if (t < 31) {
      const long long adv = (long long)(t + 1) * 64;
      const int nb = ((t + 1) & 1) * 24576;
#pragma unroll
      for (int p = 0; p < 6; ++p) gload_lds16(gsrc[p] + adv, lds + nb + ldsoff[p]);
    }
    const char* cbuf = lds + (t & 1) * 24576;
    const short8 qhv = *(const short8*)(cbuf + qoff);
    const short8 qlv = *(const short8*)(cbuf + 4096 + qoff);
#pragma unroll
    for (int ni = 0; ni < 8; ++ni) {
      const int krow = ni * 16 + l;
      const int koff = krow * 64 + ((g ^ ((krow >> 1) & 3)) << 4);
      const short8 khv = *(const short8*)(cbuf + 8192 + koff);
      const short8 klv = *(const short8*)(cbuf + 16384 + koff);
      acc[ni] = mfma16(qhv, khv, acc[ni]);
      acc[ni] = mfma16(qhv, klv, acc[ni]);
      acc[ni] = mfma16(qlv, khv, acc[ni]);
    }
  }
  __syncthreads();  // all waves done with last QK tile -> bufs reusable

  // ---- V staging setup (dbuf 16KB chunks: 128h x 64m)
  const char* vsrc[4];
  int vdst[4];
#pragma unroll
  for (int p = 0; p < 4; ++p) {
    const int gix = p * 256 + tid;
    const int vh = gix >> 3, vsl = gix & 7;
    const int vmg = vsl ^ (vh & 7);
    vsrc[p] = (const char*)(VT + (size_t)vh * Mc + krow0 + vmg * 8);
    vdst[p] = gix * 16;
  }
  const long long hstep = (long long)Mc * 256;  // bytes per hc step (128 VT rows)

  // pre-issue V chunk 0 (hidden under top-k)
#pragma unroll
  for (int p = 0; p < 4; ++p) gload_lds16(vsrc[p], lds + 16384 + vdst[p]);

  // ---- exact top-32 + softmax
  const float s_scale = 1.0f / 32.0f;
  float vc[4][8];
  float rmax[4], ssum[4];
  unsigned int sel[4];
#pragma unroll
  for (int j = 0; j < 4; ++j) {
#pragma unroll
    for (int ni = 0; ni < 8; ++ni) vc[j][ni] = acc[ni][j] * s_scale;
    ssum[j] = 0.f;
    sel[j] = 0u;
    rmax[j] = 0.f;
  }
#pragma unroll 1
  for (int t = 0; t < 32; ++t) {
#pragma unroll
    for (int j = 0; j < 4; ++j) {
      float bv = vc[j][0];
      int bi = 0;
#pragma unroll
      for (int i = 1; i < 8; ++i)
        if (vc[j][i] > bv) { bv = vc[j][i]; bi = i; }
      float cv = bv;
      int cc = (bi << 4) | l;  // col = (bi<<4)|l; ties -> min col (matches lax.top_k)
      dpp_step<0xB1>(cv, cc);   // quad_perm(1,0,3,2): xor 1
      dpp_step<0x4E>(cv, cc);   // quad_perm(2,3,0,1): xor 2
      dpp_step<0x141>(cv, cc);  // row_half_mirror
      dpp_step<0x140>(cv, cc);  // row_mirror
      if (t == 0) rmax[j] = cv;
      ssum[j] += __expf(cv - rmax[j]);
      const bool hit = ((cc & 15) == l);
      const int ci = cc >> 4;
#pragma unroll
      for (int i = 0; i < 8; ++i)
        if (hit && ci == i) vc[j][i] = -__builtin_inff();
      sel[j] |= (hit ? (1u << ci) : 0u);
    }
  }
  // P store (bf16, swizzled) into lds[0..16K) — overwrites QK buf0 (done)
#pragma unroll
  for (int j = 0; j < 4; ++j) {
    const int qr = wid * 16 + g * 4 + j;
    const float isum = 1.0f / ssum[j];
#pragma unroll
    for (int ni = 0; ni < 8; ++ni) {
      const float p =
          ((sel[j] >> ni) & 1u) ? (__expf(acc[ni][j] * s_scale - rmax[j]) * isum) : 0.0f;
      const int col = ni * 16 + l;
      const int addr = qr * 256 + ((col * 2) ^ ((qr & 7) << 4));
      *(unsigned short*)(lds + addr) = f2bf(p);
    }
  }

  // ---- phase 2: out = P @ V over 16 chunks (8 hc x 2 mc); wave owns 32 h per chunk.
  f32x4 a2[4][2];
#pragma unroll 1
  for (int c = 0; c < 16; ++c) {
    __syncthreads();  // drains chunk c's stage (issued one chunk ago) + flushes P (c==0)
    if (c < 15) {
      const int c1 = c + 1;
      const long long soff = (long long)(c1 >> 1) * hstep + (c1 & 1) * 128;
      const int nb = 16384 + (c1 & 1) * 16384;
#pragma unroll
      for (int p = 0; p < 4; ++p) gload_lds16(vsrc[p] + soff, lds + nb + vdst[p]);
    }
    const int mc = c & 1;
    const char* vbb = lds + 16384 + mc * 16384;
    if (mc == 0) {
#pragma unroll
      for (int i = 0; i < 4; ++i)
#pragma unroll
        for (int j = 0; j < 2; ++j) a2[i][j] = (f32x4){0.f, 0.f, 0.f, 0.f};
    }
#pragma unroll
    for (int ks = 0; ks < 2; ++ks) {
      short8 pa[4];
#pragma unroll
      for (int mi = 0; mi < 4; ++mi) {
        const int q = mi * 16 + l;
        pa[mi] = *(const short8*)(lds + q * 256 +
                                  ((mc * 128 + ks * 64 + g * 16) ^ ((q & 7) << 4)));
      }
#pragma unroll
      for (int ni = 0; ni < 2; ++ni) {
        const int hl = wid * 32 + ni * 16 + l;
        const short8 vb =
            *(const short8*)(vbb + hl * 128 + ((ks * 64 + g * 16) ^ ((hl & 7) << 4)));
#pragma unroll
        for (int mi = 0; mi < 4; ++mi) a2[mi][ni] = mfma16(pa[mi], vb, a2[mi][ni]);
      }
    }
    if (mc == 1) {
      const int hc = c >> 1;
#pragma unroll
      for (int mi = 0; mi < 4; ++mi)
#pragma unroll
        for (int ni = 0; ni < 2; ++ni) {
          const int h = hc * 128 + wid * 32 + ni * 16 + l;
#pragma unroll
          for (int jj = 0; jj < 4; ++jj) {
            const int q = mi * 16 + g * 4 + jj;
            float o = a2[mi][ni][jj];
            o = (o >= 0.f) ? o : 0.01f * o;
            const size_t gi = (size_t)(gr0 + qrow0 + q) * 1024 + h;
            out[gi] = o + x[gi];
          }
        }
    }
  }
}

// ---------------- row LayerNorm in-place on d_out
__global__ __launch_bounds__(256) void ln_kernel(
    float* __restrict__ out, const float* __restrict__ gamma, const float* __restrict__ beta)
{
  const int row = blockIdx.x;
  float* p = out + (size_t)row * 1024;
  const int tidx = threadIdx.x;
  float4 v = *((const float4*)p + tidx);
  float s = v.x + v.y + v.z + v.w;
  float s2 = v.x * v.x + v.y * v.y + v.z * v.z + v.w * v.w;
#pragma unroll
  for (int st = 0; st < 6; ++st) {
    const int mk = 1 << st;
    s += __shfl_xor(s, mk, 64);
    s2 += __shfl_xor(s2, mk, 64);
  }
  __shared__ float red[8];
  const int wid = tidx >> 6, lane = tidx & 63;
  if (lane == 0) { red[wid] = s; red[4 + wid] = s2; }
  __syncthreads();
  s = red[0] + red[1] + red[2] + red[3];
  s2 = red[4] + red[5] + red[6] + red[7];
  const float mu = s * (1.0f / 1024.0f);
  float var = s2 * (1.0f / 1024.0f) - mu * mu;
  var = var < 0.f ? 0.f : var;
  const float rstd = 1.0f / sqrtf(var + 1e-5f);
  float4 gm = *((const float4*)gamma + tidx);
  float4 bt = *((const float4*)beta + tidx);
  v.x = (v.x - mu) * rstd * gm.x + bt.x;
  v.y = (v.y - mu) * rstd * gm.y + bt.y;
  v.z = (v.z - mu) * rstd * gm.z + bt.z;
  v.w = (v.w - mu) * rstd * gm.w + bt.w;
  *((float4*)p + tidx) = v;
}

extern "C" void kernel_launch(void* const* d_in, const int* in_sizes, int n_in,
                              void* d_out, int out_size, void* d_ws, size_t ws_size,
                              hipStream_t stream)
{
  (void)in_sizes; (void)n_in; (void)out_size;
  const float* x = (const float*)d_in[0];
  const float* Wq = (const float*)d_in[1];
  const float* bq = (const float*)d_in[2];
  const float* Wk = (const float*)d_in[3];
  const float* bk = (const float*)d_in[4];
  (void)bk;
  const float* Wv = (const float*)d_in[5];
  const float* bv = (const float*)d_in[6];
  const float* gamma = (const float*)d_in[7];
  const float* beta = (const float*)d_in[8];
  float* out = (float*)d_out;

  char* ws = (char*)d_ws;
  size_t off = 0;
  auto alloc = [&](size_t n) {
    char* p = ws + off;
    off = (off + n + 255) & ~(size_t)255;
    return p;
  };
  unsigned short* Wvh = (unsigned short*)alloc(1024ull * 1024 * 2);
  float* Gt = (float*)alloc(1024ull * 1024 * 4);
  unsigned short* Gth = (unsigned short*)alloc(1024ull * 1024 * 2);
  unsigned short* Gtl = (unsigned short*)alloc(1024ull * 1024 * 2);
  float* wv = (float*)alloc(1024 * 4);
  const size_t fixed = off;
  const size_t perBatch = 4096ull * 1024 * 2 * 5;  // xh,xl,Yh,Yl,VT per 4096 rows
  int NB = 8;
  while (NB > 1 && fixed + (size_t)NB * perBatch + 8192 > ws_size) NB >>= 1;
  const int M = NB * 4096;
  unsigned short* xh = (unsigned short*)alloc((size_t)M * 1024 * 2);
  unsigned short* xl = (unsigned short*)alloc((size_t)M * 1024 * 2);
  unsigned short* Yh = (unsigned short*)alloc((size_t)M * 1024 * 2);
  unsigned short* Yl = (unsigned short*)alloc((size_t)M * 1024 * 2);
  unsigned short* VT = (unsigned short*)alloc((size_t)M * 1024 * 2);

  hipLaunchKernelGGL(conv_wv_kernel, dim3(512), dim3(256), 0, stream, Wv, Wvh);
  hipLaunchKernelGGL(wv_kernel, dim3(4), dim3(256), 0, stream, Wk, bq, wv);
  hipLaunchKernelGGL(gt_kernel, dim3(16, 16), dim3(256), 0, stream, Wq, Wk, Gt);
  hipLaunchKernelGGL(gsplit_kernel, dim3(512), dim3(256), 0, stream, Gt, Gth, Gtl);
  for (int c = 0; c < 8 / NB; ++c) {
    const int r0 = c * M;
    hipLaunchKernelGGL(conv_x_kernel, dim3(M / 2), dim3(256), 0, stream,
                       x + (size_t)r0 * 1024, xh, xl);
    // Y' = x . Gt^T + wv (col bias, f32 add before split)
    hipLaunchKernelGGL((gemm256_kernel<true, 2, false, 2>), dim3((M / 256) * 4), dim3(512), 0,
                       stream, xh, xl, Gth, Gtl, wv, Yh, Yl, 1024, 1024, 1024);
    // V^T: A = Wvh (1024 x 1024), B = xh (M x 1024), C = VT (1024 x M)
    hipLaunchKernelGGL((gemm256_kernel<false, 1, true, 2>), dim3(4 * (M / 256)), dim3(512), 0,
                       stream, Wvh, (const unsigned short*)nullptr, xh,
                       (const unsigned short*)nullptr, bv, VT, (unsigned short*)nullptr,
                       1024, 1024, M);
    hipLaunchKernelGGL(attn_kernel, dim3(M / 64), dim3(256), 0, stream,
                       Yh, Yl, xh, xl, VT, x, out, M, r0);
  }
  hipLaunchKernelGGL(ln_kernel, dim3(32768), dim3(256), 0, stream, out, gamma, beta);
}